// Round 10
// baseline (297.255 us; speedup 1.0000x reference)
//
#include <hip/hip_runtime.h>
#include <hip/hip_bf16.h>

// SimpleFuzzyAttention: B=2, S=2048, D=1024, H=16, DK=64
// fz(s) is univariate -> packed bf16 (v0, delta) LUT of g(s)=exp(fz(s)-bound);
// bound = 16/temp (analytic max of fz); constant cancels in softmax.
// R13: GEMM tile 128x128 -> 256x256 (m112: 792 TF at 1 block/CU vs this
// structure's ~215 TF effective). 512 threads, 8 waves (2Mx4N), 128x64/wave,
// 32 MFMA : 12 ds_read_b128 per BK=32 step, dbuf LDS 64 KB, 1 barrier/step.
// R12's XCD swizzle + BN=64 reverted (measured net -6us). Staging/fragment
// swizzle algebra inherited from the verified 128^2 kernel (scale-invariant:
// (row>>1)&3 == (l15>>1)&3 for any 16-aligned wave base).
// Flash/prep untouched from R11 (flash measured 75.1us).

#define S_LEN 2048
#define DMODEL 1024
#define NHEAD 16
#define DKH 64
#define NLUT 2048
#define LUT_MIN (-10.0f)
#define LUT_MAX (10.0f)

typedef __attribute__((ext_vector_type(8))) short bfx8;   // 8 bf16 (4 VGPRs)
typedef __attribute__((ext_vector_type(4))) float fx4;    // MFMA C/D 16x16
typedef __attribute__((ext_vector_type(16))) float fx16;  // MFMA C/D 32x32
typedef __attribute__((ext_vector_type(4))) unsigned ux4;

__device__ __forceinline__ short f2bf(float x) {
    unsigned u = __builtin_bit_cast(unsigned, x);
    u = (u + 0x7fffu + ((u >> 16) & 1u)) >> 16;   // RNE
    return (short)u;
}

__device__ __forceinline__ unsigned cvt_pk_bf16(float lo, float hi) {
    unsigned r;
    asm("v_cvt_pk_bf16_f32 %0, %1, %2" : "=v"(r) : "v"(lo), "v"(hi));
    return r;
}

// v_permlane32_swap_b32: after, a = {a_lo, b_lo}, b = {a_hi, b_hi}.
__device__ __forceinline__ void plane_swap(unsigned& a, unsigned& b) {
    asm volatile("v_permlane32_swap_b32 %0, %1" : "+v"(a), "+v"(b));
}

__device__ __forceinline__ void stage8_f32(const float* __restrict__ src, short* dst) {
    float4 a = *(const float4*)(src);
    float4 b = *(const float4*)(src + 4);
    bfx8 r;
    r[0] = f2bf(a.x); r[1] = f2bf(a.y); r[2] = f2bf(a.z); r[3] = f2bf(a.w);
    r[4] = f2bf(b.x); r[5] = f2bf(b.y); r[6] = f2bf(b.z); r[7] = f2bf(b.w);
    *(bfx8*)dst = r;
}

// global -> LDS direct 16B copy (LDS base wave-uniform; lane*16 implied)
__device__ __forceinline__ void gload_lds16(const void* g, void* l) {
    __builtin_amdgcn_global_load_lds(
        (const __attribute__((address_space(1))) unsigned int*)g,
        (__attribute__((address_space(3))) unsigned int*)l, 16, 0, 0);
}

// ---------------------------------------------------------------------------
// Parallel LUT slice: 8 blocks x 256 points. lutp[j] = bf16(g[j]) |
// bf16(g[j+1]-g[j])<<16, g = exp(fz - 16/temp). No division, no reduction.
// ---------------------------------------------------------------------------
__device__ void lut_slice(const float* __restrict__ centers, const float* __restrict__ widths,
                          const float* __restrict__ temp, unsigned* __restrict__ lutp,
                          int slice) {
    __shared__ float cs[48], iw[48];
    __shared__ float gsh[257];
    int tid = threadIdx.x;
    if (tid < 48) {
        cs[tid] = centers[tid];
        float w = widths[tid];
        iw[tid] = -0.5f / (w * w);
    }
    __syncthreads();
    float invT = 1.0f / temp[0];
    const float step = (LUT_MAX - LUT_MIN) / (float)(NLUT - 1);
    float bound = 16.0f * invT;
    int base = slice * 256;
    #pragma unroll 1
    for (int idx = tid; idx < 257; idx += 256) {   // tid 0 also does the halo
        int i = base + idx; if (i > NLUT - 1) i = NLUT - 1;
        float s = LUT_MIN + step * (float)i;
        float a = 0.0f;
        #pragma unroll
        for (int j = 0; j < 48; j++) {
            float d = s - cs[j];
            a += expf(d * d * iw[j]);
        }
        float fz = a * (1.0f / 3.0f) * invT;
        gsh[idx] = expf(fz - bound);
    }
    __syncthreads();
    float g0 = gsh[tid];
    unsigned lo = (unsigned short)f2bf(g0);
    unsigned hi = (unsigned short)f2bf(gsh[tid + 1] - g0);
    lutp[base + tid] = lo | (hi << 16);
}

__global__ void build_lut_pk(const float* centers, const float* widths,
                             const float* temp, unsigned* lutp) {
    lut_slice(centers, widths, temp, lutp, blockIdx.x);
}

// ---------------------------------------------------------------------------
// fp32 -> bf16 cast (fallback path), 8 elems/thread
// ---------------------------------------------------------------------------
__global__ void cast_bf16(const float* __restrict__ src, short* __restrict__ dst, int n8) {
    int i = blockIdx.x * 256 + threadIdx.x;
    if (i < n8) stage8_f32(src + (size_t)i * 8, dst + (size_t)i * 8);
}

// ---------------------------------------------------------------------------
// Fused prep: grid 1032. Blocks [0,1024) grid-stride the 8192 copy units
// ([0,6144)=inputs, [6144,8192)=weights); blocks [1024,1032) build the LUT.
// ---------------------------------------------------------------------------
__global__ void prep_all(const float* q, const float* kin, const float* v,
        const float* wq, const float* wk, const float* wv, const float* wo,
        short* xq, short* xk, short* xv,
        short* bwq, short* bwk, short* bwv, short* bwo,
        const float* centers, const float* widths, const float* temp,
        unsigned* lutp) {
    int bid = blockIdx.x;
    if (bid >= 1024) {
        lut_slice(centers, widths, temp, lutp, bid - 1024);
        return;
    }
    for (int vb = bid; vb < 8192; vb += 1024) {
        const float* src; short* dst; int blk;
        if (vb < 6144) {
            int y = vb >> 11; blk = vb & 2047;
            src = (y == 0) ? q : (y == 1) ? kin : v;
            dst = (y == 0) ? xq : (y == 1) ? xk : xv;
        } else {
            int y = (vb - 6144) >> 9; blk = (vb - 6144) & 511;
            src = (y == 0) ? wq : (y == 1) ? wk : (y == 2) ? wv : wo;
            dst = (y == 0) ? bwq : (y == 1) ? bwk : (y == 2) ? bwv : bwo;
        }
        size_t i = (size_t)blk * 256 + threadIdx.x;   // always in range (exact)
        stage8_f32(src + i * 8, (short*)dst + i * 8);
    }
}

// ---------------------------------------------------------------------------
// bf16 BT-GEMM, 256x256 tile, BK=32, 512 threads (8 waves, 2Mx4N), dbuf LDS,
// prefetch-before-compute, one barrier per k-step. 1D grid:
// id -> x = id&3 (n-tile), y = (id>>2)&15 (m-tile), z = id>>6 (job).
// C[m,n] = (sum_k A[m,k]*W[n,k] + bias[n]) * scale.
// mode 0: bf16 [B,H,S,DK]; 1: bf16 [B,H,DK,S]; 2: fp32 [M,N]
// ---------------------------------------------------------------------------
struct GemmJob {
    const short* A; const short* W; const float* bias;
    short* obf; float* of32; int mode; float scale;
};

__global__ __launch_bounds__(512, 2) void gemm256(GemmJob j0, GemmJob j1, GemmJob j2) {
    __shared__ __align__(16) short As[2][256 * 32];   // 2 x 16 KB, swizzled
    __shared__ __align__(16) short Bs[2][256 * 32];   // 2 x 16 KB

    int id = blockIdx.x;
    int x = id & 3, y = (id >> 2) & 15, z = id >> 6;
    GemmJob jb = (z == 0) ? j0 : (z == 1) ? j1 : j2;

    int tid = threadIdx.x, wave = tid >> 6, lane = tid & 63, quad = lane >> 4, l15 = lane & 15;
    int m0 = y * 256, n0 = x * 256;
    int wm = (wave >> 2) * 128, wn = (wave & 3) * 64;

    fx4 acc[8][4];
    #pragma unroll
    for (int i = 0; i < 8; i++)
        #pragma unroll
        for (int j = 0; j < 4; j++)
            #pragma unroll
            for (int r = 0; r < 4; r++) acc[i][j][r] = 0.0f;

    int fc = (quad ^ ((l15 >> 1) & 3)) * 8;        // swizzled frag chunk (shorts)

    // staging lane geometry: 1024 chunks of 16B per buffer, 2 per thread
    int srow[2], sgc[2];
    #pragma unroll
    for (int r = 0; r < 2; r++) {
        int slot = r * 512 + wave * 64 + lane;     // -> 256 rows x 4 chunks
        srow[r] = slot >> 2;
        sgc[r] = (slot & 3) ^ ((srow[r] >> 1) & 3);
    }

    auto stage = [&](int k0, int buf) {
        #pragma unroll
        for (int r = 0; r < 2; r++) {
            gload_lds16(jb.A + (size_t)(m0 + srow[r]) * DMODEL + k0 + sgc[r] * 8,
                        &As[buf][(r * 512 + wave * 64) * 8]);
            gload_lds16(jb.W + (size_t)(n0 + srow[r]) * DMODEL + k0 + sgc[r] * 8,
                        &Bs[buf][(r * 512 + wave * 64) * 8]);
        }
    };

    stage(0, 0);
    __syncthreads();                 // vmcnt(0) drain of prologue stage
    int buf = 0;
    for (int k0 = 0; k0 < DMODEL; k0 += 32) {
        if (k0 + 32 < DMODEL) stage(k0 + 32, buf ^ 1);   // prefetch next tile
        bfx8 af[8], bfr[4];
        #pragma unroll
        for (int i = 0; i < 8; i++) af[i] = *(const bfx8*)(&As[buf][(wm + i * 16 + l15) * 32 + fc]);
        #pragma unroll
        for (int j = 0; j < 4; j++) bfr[j] = *(const bfx8*)(&Bs[buf][(wn + j * 16 + l15) * 32 + fc]);
        #pragma unroll
        for (int i = 0; i < 8; i++)
            #pragma unroll
            for (int j = 0; j < 4; j++)
                acc[i][j] = __builtin_amdgcn_mfma_f32_16x16x32_bf16(af[i], bfr[j], acc[i][j], 0, 0, 0);
        __syncthreads();             // drains prefetch (had full compute to fly)
        buf ^= 1;
    }

    // epilogue: C/D layout col=lane&15 (n), row=quad*4+reg (m)
    #pragma unroll
    for (int j = 0; j < 4; j++) {
        int n = n0 + wn + j * 16 + l15;
        float bv = jb.bias[n];
        #pragma unroll
        for (int i = 0; i < 8; i++) {
            #pragma unroll
            for (int r = 0; r < 4; r++) {
                int m = m0 + wm + i * 16 + quad * 4 + r;
                float v = (acc[i][j][r] + bv) * jb.scale;
                if (jb.mode == 0) {
                    int b = m >> 11, s = m & 2047, h = n >> 6, dk = n & 63;
                    jb.obf[(((size_t)(b * NHEAD + h)) * S_LEN + s) * DKH + dk] = f2bf(v);
                } else if (jb.mode == 1) {
                    int b = m >> 11, s = m & 2047, h = n >> 6, dk = n & 63;
                    jb.obf[(((size_t)(b * NHEAD + h)) * DKH + dk) * S_LEN + s] = f2bf(v);
                } else {
                    jb.of32[(size_t)m * DMODEL + n] = v;
                }
            }
        }
    }
}

// ---------------------------------------------------------------------------
// Fuzzy flash attention, unchanged from R11 (measured 75.1 us): 32x32x16
// MFMA, in-register P; K/V staged in LDS with phi(r)=(r^(r>>3))&7 swizzle;
// single (v0,delta) LUT; den via ones-MFMA; launch_bounds(256,4) — do NOT
// raise (R10: forcing 6 waves/EU spilled accumulators, 2.5x regression).
// ---------------------------------------------------------------------------
__global__ __launch_bounds__(256, 4) void flash_fuzzy(const short* __restrict__ Qb,
        const short* __restrict__ Kb, const short* __restrict__ VTb,
        const unsigned* __restrict__ lutg, short* __restrict__ AO) {
    __shared__ __align__(16) short Ks[64 * 64];     // 8 KB [kv][dk], phi-swizzled
    __shared__ __align__(16) short Vs[64 * 64];     // 8 KB [dk][kv], phi-swizzled
    __shared__ unsigned lut[NLUT];                  // 8 KB (v0, delta) bf16 pairs
    __shared__ float dbuf[128];                     // den exchange

    int tid = threadIdx.x, wave = tid >> 6, lane = tid & 63;
    int l31 = lane & 31, hi = lane >> 5;
    int wq = wave >> 1, st = wave & 1;
    int q0 = blockIdx.x * 64, bh = blockIdx.y;
    const short* Qp = Qb + (size_t)bh * S_LEN * DKH;
    const short* Kp = Kb + (size_t)bh * S_LEN * DKH;
    const short* Vp = VTb + (size_t)bh * DKH * S_LEN;

    #pragma unroll
    for (int i = tid; i < NLUT / 4; i += 256)
        ((uint4*)lut)[i] = ((const uint4*)lutg)[i];

    // Q as B-operand: lane supplies B[k=hi*8+j][q=l31] = Q[q0+wq*32+l31][k]
    bfx8 aq[4];
    #pragma unroll
    for (int ks = 0; ks < 4; ks++)
        aq[ks] = *(const bfx8*)(Qp + (size_t)(q0 + wq * 32 + l31) * DKH + ks * 16 + hi * 8);

    bfx8 ones;
    #pragma unroll
    for (int i = 0; i < 8; i++) ones[i] = (short)0x3F80;  // bf16 1.0

    fx16 oacc[2];
    fx16 dacc;
    #pragma unroll
    for (int r = 0; r < 16; r++) dacc[r] = 0.0f;
    #pragma unroll
    for (int dt = 0; dt < 2; dt++)
        #pragma unroll
        for (int r = 0; r < 16; r++) oacc[dt][r] = 0.0f;

    const float invh = (float)(NLUT - 1) / (LUT_MAX - LUT_MIN);
    const float xoff = -LUT_MIN * invh;

    // staging geometry: 512 slots of 16B per buffer, 2 per thread;
    // chunk swizzled by phi(row) = (row ^ (row>>3)) & 7
    int srow[2], sgc[2];
    #pragma unroll
    for (int r = 0; r < 2; r++) {
        int slot = (wave * 2 + r) * 64 + lane;
        srow[r] = slot >> 3;
        sgc[r] = (slot & 7) ^ ((srow[r] ^ (srow[r] >> 3)) & 7);
    }

    int krow = st * 32 + l31;
    int kphi = (krow ^ (krow >> 3)) & 7;

    for (int t0 = 0; t0 < S_LEN; t0 += 64) {
        __syncthreads();                 // all waves done reading tile t0-64
        #pragma unroll
        for (int r = 0; r < 2; r++) {
            gload_lds16(Kp + (size_t)(t0 + srow[r]) * DKH + sgc[r] * 8,
                        &Ks[((wave * 2 + r) * 64) * 8]);
            gload_lds16(Vp + (size_t)srow[r] * S_LEN + t0 + sgc[r] * 8,
                        &Vs[((wave * 2 + r) * 64) * 8]);
        }
        __syncthreads();                 // staging complete

        // S^T[kv32 (this wave's half)][q32] = K . Q^T over dk=64 (4 k-steps)
        fx16 sac;
        #pragma unroll
        for (int r = 0; r < 16; r++) sac[r] = 0.0f;
        #pragma unroll
        for (int ks = 0; ks < 4; ks++) {
            bfx8 kf = *(const bfx8*)(&Ks[krow * 64 + (((ks * 2 + hi) ^ kphi) * 8)]);
            sac = __builtin_amdgcn_mfma_f32_32x32x16_bf16(kf, aq[ks], sac, 0, 0, 0);
        }

        // p = g(s): one b32 (v0, delta) gather + fma lerp; pack pairs to bf16
        unsigned w[8];
        #pragma unroll
        for (int t = 0; t < 8; t++) {
            float pv[2];
            #pragma unroll
            for (int u = 0; u < 2; u++) {
                float s = sac[t * 2 + u];
                float x = fmaf(s, invh, xoff);
                x = __builtin_amdgcn_fmed3f(x, 0.0f, (float)(NLUT - 1));
                int j = (int)x;
                float f = x - (float)j;
                unsigned pr = lut[j];
                float v0 = __builtin_bit_cast(float, pr << 16);
                float dl = __builtin_bit_cast(float, pr & 0xffff0000u);
                pv[u] = fmaf(f, dl, v0);
            }
            w[t] = cvt_pk_bf16(pv[0], pv[1]);
        }

        // redistribute across lane halves -> PV B-fragments
        plane_swap(w[0], w[2]); plane_swap(w[1], w[3]);
        plane_swap(w[4], w[6]); plane_swap(w[5], w[7]);
        ux4 b0v = {w[0], w[1], w[2], w[3]};
        ux4 b1v = {w[4], w[5], w[6], w[7]};
        bfx8 pb0 = __builtin_bit_cast(bfx8, b0v);
        bfx8 pb1 = __builtin_bit_cast(bfx8, b1v);

        // O^T[dk][q] += VT . P^T   (2 dk-tiles x 2 k-steps)
        #pragma unroll
        for (int dt = 0; dt < 2; dt++) {
            int row = dt * 32 + l31;
            int vphi = (row ^ (row >> 3)) & 7;
            bfx8 v0f = *(const bfx8*)(&Vs[row * 64 + (((st * 4 + 0 + hi) ^ vphi) * 8)]);
            bfx8 v1f = *(const bfx8*)(&Vs[row * 64 + (((st * 4 + 2 + hi) ^ vphi) * 8)]);
            oacc[dt] = __builtin_amdgcn_mfma_f32_32x32x16_bf16(v0f, pb0, oacc[dt], 0, 0, 0);
            oacc[dt] = __builtin_amdgcn_mfma_f32_32x32x16_bf16(v1f, pb1, oacc[dt], 0, 0, 0);
        }
        // den[q] += sum_kv P[kv][q] on the matrix pipe (rows all equal)
        dacc = __builtin_amdgcn_mfma_f32_32x32x16_bf16(ones, pb0, dacc, 0, 0, 0);
        dacc = __builtin_amdgcn_mfma_f32_32x32x16_bf16(ones, pb1, dacc, 0, 0, 0);
    }

    float den = dacc[0];   // den[q=l31] for this wave's kv-half (rows equal)

    // combine kv halves: st=1 waves stash to LDS (Ks/Vs dead), st=0 finalize
    __syncthreads();
    float* obuf = (wq == 0) ? (float*)Ks : (float*)Vs;   // 8 KB each
    if (st == 1) {
        #pragma unroll
        for (int dt = 0; dt < 2; dt++)
            #pragma unroll
            for (int r = 0; r < 16; r++)
                obuf[(dt * 16 + r) * 64 + lane] = oacc[dt][r];
        dbuf[wq * 64 + lane] = den;
    }
    __syncthreads();
    if (st == 0) {
        float dtot = den + dbuf[wq * 64 + lane];
        int b = bh >> 4, h = bh & 15;
        #pragma unroll
        for (int dt = 0; dt < 2; dt++) {
            #pragma unroll
            for (int r = 0; r < 16; r++) {
                float o = oacc[dt][r] + obuf[(dt * 16 + r) * 64 + lane];
                int dk = dt * 32 + (r & 3) + 8 * (r >> 2) + 4 * hi;
                int q = q0 + wq * 32 + l31;
                AO[((size_t)(b * S_LEN + q)) * DMODEL + h * DKH + dk] = f2bf(o / dtot);
            }
        }
    }
}

// ---------------------------------------------------------------------------
extern "C" void kernel_launch(void* const* d_in, const int* in_sizes, int n_in,
                              void* d_out, int out_size, void* d_ws, size_t ws_size,
                              hipStream_t stream) {
    const float* query   = (const float*)d_in[0];
    const float* key_in  = (const float*)d_in[1];
    const float* value   = (const float*)d_in[2];
    const float* w_q     = (const float*)d_in[3];
    const float* b_q     = (const float*)d_in[4];
    const float* w_k     = (const float*)d_in[5];
    const float* b_k     = (const float*)d_in[6];
    const float* w_v     = (const float*)d_in[7];
    const float* b_v     = (const float*)d_in[8];
    const float* w_o     = (const float*)d_in[9];
    const float* b_o     = (const float*)d_in[10];
    const float* centers = (const float*)d_in[11];
    const float* widths  = (const float*)d_in[12];
    const float* temp    = (const float*)d_in[13];

    char* p = (char*)d_ws;
    auto alloc = [&](size_t bytes) -> void* {
        void* r = (void*)p;
        p += (bytes + 255) & ~(size_t)255;
        return r;
    };
    const size_t nBHSD = (size_t)2 * NHEAD * S_LEN * DKH;    // 4.19M elems
    const size_t nW    = (size_t)DMODEL * DMODEL;            // 1.05M elems
    unsigned* lutp = (unsigned*)alloc(NLUT * 4);
    short* Qb  = (short*)alloc(nBHSD * 2);
    short* Kb  = (short*)alloc(nBHSD * 2);
    short* VTb = (short*)alloc(nBHSD * 2);

    char* save = p;
    short* xq  = (short*)alloc(nBHSD * 2);
    short* xk  = (short*)alloc(nBHSD * 2);
    short* xv  = (short*)alloc(nBHSD * 2);
    short* bwq = (short*)alloc(nW * 2);
    short* bwk = (short*)alloc(nW * 2);
    short* bwv = (short*)alloc(nW * 2);
    short* bwo = (short*)alloc(nW * 2);
    bool fused = ((size_t)(p - (char*)d_ws) <= ws_size);

    dim3 blk(256), blk2(512);
    dim3 fg(32, 32);
    GemmJob JO;

    if (fused) {
        short* AO = xq;   // alias: xq dead after QKV gemm
        prep_all<<<dim3(1032), blk, 0, stream>>>(query, key_in, value, w_q, w_k, w_v, w_o,
                xq, xk, xv, bwq, bwk, bwv, bwo, centers, widths, temp, lutp);
        GemmJob JQ = {xq, bwq, b_q, Qb,  nullptr, 0, 0.125f};   // 1/sqrt(64) folded
        GemmJob JK = {xk, bwk, b_k, Kb,  nullptr, 0, 1.0f};
        GemmJob JV = {xv, bwv, b_v, VTb, nullptr, 1, 1.0f};
        gemm256<<<dim3(192), blk2, 0, stream>>>(JQ, JK, JV);
        flash_fuzzy<<<fg, blk, 0, stream>>>(Qb, Kb, VTb, lutp, AO);
        JO = {AO, bwo, b_o, nullptr, (float*)d_out, 2, 1.0f};
        gemm256<<<dim3(64), blk2, 0, stream>>>(JO, JO, JO);
    } else {
        // serial fallback: reuse one x-buffer + one w-buffer (~36 MB total)
        p = save;
        short* xf = (short*)alloc(nBHSD * 2);
        short* wb = (short*)alloc(nW * 2);
        short* AO = xf;
        const int n8x = (int)(nBHSD / 8), n8w = (int)(nW / 8);
        dim3 cg((n8x + 255) / 256), cw((n8w + 255) / 256);
        build_lut_pk<<<dim3(8), blk, 0, stream>>>(centers, widths, temp, lutp);
        cast_bf16<<<cg, blk, 0, stream>>>(query, xf, n8x);
        cast_bf16<<<cw, blk, 0, stream>>>(w_q, wb, n8w);
        JO = {xf, wb, b_q, Qb, nullptr, 0, 0.125f};
        gemm256<<<dim3(64), blk2, 0, stream>>>(JO, JO, JO);
        cast_bf16<<<cg, blk, 0, stream>>>(key_in, xf, n8x);
        cast_bf16<<<cw, blk, 0, stream>>>(w_k, wb, n8w);
        JO = {xf, wb, b_k, Kb, nullptr, 0, 1.0f};
        gemm256<<<dim3(64), blk2, 0, stream>>>(JO, JO, JO);
        cast_bf16<<<cg, blk, 0, stream>>>(value, xf, n8x);
        cast_bf16<<<cw, blk, 0, stream>>>(w_v, wb, n8w);
        JO = {xf, wb, b_v, VTb, nullptr, 1, 1.0f};
        gemm256<<<dim3(64), blk2, 0, stream>>>(JO, JO, JO);
        flash_fuzzy<<<fg, blk, 0, stream>>>(Qb, Kb, VTb, lutp, AO);
        cast_bf16<<<cw, blk, 0, stream>>>(w_o, wb, n8w);
        JO = {AO, wb, b_o, nullptr, (float*)d_out, 2, 1.0f};
        gemm256<<<dim3(64), blk2, 0, stream>>>(JO, JO, JO);
    }
}

// Round 11
// 296.255 us; speedup vs baseline: 1.0034x; 1.0034x over previous
//
#include <hip/hip_runtime.h>
#include <hip/hip_bf16.h>

// SimpleFuzzyAttention: B=2, S=2048, D=1024, H=16, DK=64
// fz(s) is univariate -> packed bf16 (v0, delta) LUT of g(s)=exp(fz(s)-bound);
// bound = 16/temp (analytic max of fz); constant cancels in softmax.
// R14: single fix on R13. gemm256's launch_bounds(512,2) squeezed the
// allocator (VGPR_Count=120 < 176-reg live set) -> accumulator SPILL
// (FETCH 55.5MB vs 30 expected, WRITE 43 vs 24, MfmaUtil 9.7%). Change to
// launch_bounds(512,1): <=512 regs/wave, no spill. Occupancy unaffected:
// grids (192/64 blocks) already give <=1 block/CU; LDS 64KB permits 2.
// m112 proves the 256^2 2-barrier structure reaches 792 TF at 1 block/CU.
// Flash/prep untouched from R11 (flash measured 75.1us).

#define S_LEN 2048
#define DMODEL 1024
#define NHEAD 16
#define DKH 64
#define NLUT 2048
#define LUT_MIN (-10.0f)
#define LUT_MAX (10.0f)

typedef __attribute__((ext_vector_type(8))) short bfx8;   // 8 bf16 (4 VGPRs)
typedef __attribute__((ext_vector_type(4))) float fx4;    // MFMA C/D 16x16
typedef __attribute__((ext_vector_type(16))) float fx16;  // MFMA C/D 32x32
typedef __attribute__((ext_vector_type(4))) unsigned ux4;

__device__ __forceinline__ short f2bf(float x) {
    unsigned u = __builtin_bit_cast(unsigned, x);
    u = (u + 0x7fffu + ((u >> 16) & 1u)) >> 16;   // RNE
    return (short)u;
}

__device__ __forceinline__ unsigned cvt_pk_bf16(float lo, float hi) {
    unsigned r;
    asm("v_cvt_pk_bf16_f32 %0, %1, %2" : "=v"(r) : "v"(lo), "v"(hi));
    return r;
}

// v_permlane32_swap_b32: after, a = {a_lo, b_lo}, b = {a_hi, b_hi}.
__device__ __forceinline__ void plane_swap(unsigned& a, unsigned& b) {
    asm volatile("v_permlane32_swap_b32 %0, %1" : "+v"(a), "+v"(b));
}

__device__ __forceinline__ void stage8_f32(const float* __restrict__ src, short* dst) {
    float4 a = *(const float4*)(src);
    float4 b = *(const float4*)(src + 4);
    bfx8 r;
    r[0] = f2bf(a.x); r[1] = f2bf(a.y); r[2] = f2bf(a.z); r[3] = f2bf(a.w);
    r[4] = f2bf(b.x); r[5] = f2bf(b.y); r[6] = f2bf(b.z); r[7] = f2bf(b.w);
    *(bfx8*)dst = r;
}

// global -> LDS direct 16B copy (LDS base wave-uniform; lane*16 implied)
__device__ __forceinline__ void gload_lds16(const void* g, void* l) {
    __builtin_amdgcn_global_load_lds(
        (const __attribute__((address_space(1))) unsigned int*)g,
        (__attribute__((address_space(3))) unsigned int*)l, 16, 0, 0);
}

// ---------------------------------------------------------------------------
// Parallel LUT slice: 8 blocks x 256 points. lutp[j] = bf16(g[j]) |
// bf16(g[j+1]-g[j])<<16, g = exp(fz - 16/temp). No division, no reduction.
// ---------------------------------------------------------------------------
__device__ void lut_slice(const float* __restrict__ centers, const float* __restrict__ widths,
                          const float* __restrict__ temp, unsigned* __restrict__ lutp,
                          int slice) {
    __shared__ float cs[48], iw[48];
    __shared__ float gsh[257];
    int tid = threadIdx.x;
    if (tid < 48) {
        cs[tid] = centers[tid];
        float w = widths[tid];
        iw[tid] = -0.5f / (w * w);
    }
    __syncthreads();
    float invT = 1.0f / temp[0];
    const float step = (LUT_MAX - LUT_MIN) / (float)(NLUT - 1);
    float bound = 16.0f * invT;
    int base = slice * 256;
    #pragma unroll 1
    for (int idx = tid; idx < 257; idx += 256) {   // tid 0 also does the halo
        int i = base + idx; if (i > NLUT - 1) i = NLUT - 1;
        float s = LUT_MIN + step * (float)i;
        float a = 0.0f;
        #pragma unroll
        for (int j = 0; j < 48; j++) {
            float d = s - cs[j];
            a += expf(d * d * iw[j]);
        }
        float fz = a * (1.0f / 3.0f) * invT;
        gsh[idx] = expf(fz - bound);
    }
    __syncthreads();
    float g0 = gsh[tid];
    unsigned lo = (unsigned short)f2bf(g0);
    unsigned hi = (unsigned short)f2bf(gsh[tid + 1] - g0);
    lutp[base + tid] = lo | (hi << 16);
}

__global__ void build_lut_pk(const float* centers, const float* widths,
                             const float* temp, unsigned* lutp) {
    lut_slice(centers, widths, temp, lutp, blockIdx.x);
}

// ---------------------------------------------------------------------------
// fp32 -> bf16 cast (fallback path), 8 elems/thread
// ---------------------------------------------------------------------------
__global__ void cast_bf16(const float* __restrict__ src, short* __restrict__ dst, int n8) {
    int i = blockIdx.x * 256 + threadIdx.x;
    if (i < n8) stage8_f32(src + (size_t)i * 8, dst + (size_t)i * 8);
}

// ---------------------------------------------------------------------------
// Fused prep: grid 1032. Blocks [0,1024) grid-stride the 8192 copy units
// ([0,6144)=inputs, [6144,8192)=weights); blocks [1024,1032) build the LUT.
// ---------------------------------------------------------------------------
__global__ void prep_all(const float* q, const float* kin, const float* v,
        const float* wq, const float* wk, const float* wv, const float* wo,
        short* xq, short* xk, short* xv,
        short* bwq, short* bwk, short* bwv, short* bwo,
        const float* centers, const float* widths, const float* temp,
        unsigned* lutp) {
    int bid = blockIdx.x;
    if (bid >= 1024) {
        lut_slice(centers, widths, temp, lutp, bid - 1024);
        return;
    }
    for (int vb = bid; vb < 8192; vb += 1024) {
        const float* src; short* dst; int blk;
        if (vb < 6144) {
            int y = vb >> 11; blk = vb & 2047;
            src = (y == 0) ? q : (y == 1) ? kin : v;
            dst = (y == 0) ? xq : (y == 1) ? xk : xv;
        } else {
            int y = (vb - 6144) >> 9; blk = (vb - 6144) & 511;
            src = (y == 0) ? wq : (y == 1) ? wk : (y == 2) ? wv : wo;
            dst = (y == 0) ? bwq : (y == 1) ? bwk : (y == 2) ? bwv : bwo;
        }
        size_t i = (size_t)blk * 256 + threadIdx.x;   // always in range (exact)
        stage8_f32(src + i * 8, (short*)dst + i * 8);
    }
}

// ---------------------------------------------------------------------------
// bf16 BT-GEMM, 256x256 tile, BK=32, 512 threads (8 waves, 2Mx4N), dbuf LDS,
// prefetch-before-compute, one barrier per k-step. launch_bounds(512,1):
// <=512 regs/wave, no spill (R13: (512,2) spilled acc -> 102us dispatches).
// 1D grid: x = id&3 (n-tile), y = (id>>2)&15 (m-tile), z = id>>6 (job).
// C[m,n] = (sum_k A[m,k]*W[n,k] + bias[n]) * scale.
// mode 0: bf16 [B,H,S,DK]; 1: bf16 [B,H,DK,S]; 2: fp32 [M,N]
// ---------------------------------------------------------------------------
struct GemmJob {
    const short* A; const short* W; const float* bias;
    short* obf; float* of32; int mode; float scale;
};

__global__ __launch_bounds__(512, 1) void gemm256(GemmJob j0, GemmJob j1, GemmJob j2) {
    __shared__ __align__(16) short As[2][256 * 32];   // 2 x 16 KB, swizzled
    __shared__ __align__(16) short Bs[2][256 * 32];   // 2 x 16 KB

    int id = blockIdx.x;
    int x = id & 3, y = (id >> 2) & 15, z = id >> 6;
    GemmJob jb = (z == 0) ? j0 : (z == 1) ? j1 : j2;

    int tid = threadIdx.x, wave = tid >> 6, lane = tid & 63, quad = lane >> 4, l15 = lane & 15;
    int m0 = y * 256, n0 = x * 256;
    int wm = (wave >> 2) * 128, wn = (wave & 3) * 64;

    fx4 acc[8][4];
    #pragma unroll
    for (int i = 0; i < 8; i++)
        #pragma unroll
        for (int j = 0; j < 4; j++)
            #pragma unroll
            for (int r = 0; r < 4; r++) acc[i][j][r] = 0.0f;

    int fc = (quad ^ ((l15 >> 1) & 3)) * 8;        // swizzled frag chunk (shorts)

    // staging lane geometry: 1024 chunks of 16B per buffer, 2 per thread
    int srow[2], sgc[2];
    #pragma unroll
    for (int r = 0; r < 2; r++) {
        int slot = r * 512 + wave * 64 + lane;     // -> 256 rows x 4 chunks
        srow[r] = slot >> 2;
        sgc[r] = (slot & 3) ^ ((srow[r] >> 1) & 3);
    }

    auto stage = [&](int k0, int buf) {
        #pragma unroll
        for (int r = 0; r < 2; r++) {
            gload_lds16(jb.A + (size_t)(m0 + srow[r]) * DMODEL + k0 + sgc[r] * 8,
                        &As[buf][(r * 512 + wave * 64) * 8]);
            gload_lds16(jb.W + (size_t)(n0 + srow[r]) * DMODEL + k0 + sgc[r] * 8,
                        &Bs[buf][(r * 512 + wave * 64) * 8]);
        }
    };

    stage(0, 0);
    __syncthreads();                 // vmcnt(0) drain of prologue stage
    int buf = 0;
    for (int k0 = 0; k0 < DMODEL; k0 += 32) {
        if (k0 + 32 < DMODEL) stage(k0 + 32, buf ^ 1);   // prefetch next tile
        bfx8 af[8], bfr[4];
        #pragma unroll
        for (int i = 0; i < 8; i++) af[i] = *(const bfx8*)(&As[buf][(wm + i * 16 + l15) * 32 + fc]);
        #pragma unroll
        for (int j = 0; j < 4; j++) bfr[j] = *(const bfx8*)(&Bs[buf][(wn + j * 16 + l15) * 32 + fc]);
        #pragma unroll
        for (int i = 0; i < 8; i++)
            #pragma unroll
            for (int j = 0; j < 4; j++)
                acc[i][j] = __builtin_amdgcn_mfma_f32_16x16x32_bf16(af[i], bfr[j], acc[i][j], 0, 0, 0);
        __syncthreads();             // drains prefetch (had full compute to fly)
        buf ^= 1;
    }

    // epilogue: C/D layout col=lane&15 (n), row=quad*4+reg (m)
    #pragma unroll
    for (int j = 0; j < 4; j++) {
        int n = n0 + wn + j * 16 + l15;
        float bv = jb.bias[n];
        #pragma unroll
        for (int i = 0; i < 8; i++) {
            #pragma unroll
            for (int r = 0; r < 4; r++) {
                int m = m0 + wm + i * 16 + quad * 4 + r;
                float v = (acc[i][j][r] + bv) * jb.scale;
                if (jb.mode == 0) {
                    int b = m >> 11, s = m & 2047, h = n >> 6, dk = n & 63;
                    jb.obf[(((size_t)(b * NHEAD + h)) * S_LEN + s) * DKH + dk] = f2bf(v);
                } else if (jb.mode == 1) {
                    int b = m >> 11, s = m & 2047, h = n >> 6, dk = n & 63;
                    jb.obf[(((size_t)(b * NHEAD + h)) * DKH + dk) * S_LEN + s] = f2bf(v);
                } else {
                    jb.of32[(size_t)m * DMODEL + n] = v;
                }
            }
        }
    }
}

// ---------------------------------------------------------------------------
// Fuzzy flash attention, unchanged from R11 (measured 75.1 us): 32x32x16
// MFMA, in-register P; K/V staged in LDS with phi(r)=(r^(r>>3))&7 swizzle;
// single (v0,delta) LUT; den via ones-MFMA; launch_bounds(256,4) — do NOT
// raise (R10: forcing 6 waves/EU spilled accumulators, 2.5x regression).
// ---------------------------------------------------------------------------
__global__ __launch_bounds__(256, 4) void flash_fuzzy(const short* __restrict__ Qb,
        const short* __restrict__ Kb, const short* __restrict__ VTb,
        const unsigned* __restrict__ lutg, short* __restrict__ AO) {
    __shared__ __align__(16) short Ks[64 * 64];     // 8 KB [kv][dk], phi-swizzled
    __shared__ __align__(16) short Vs[64 * 64];     // 8 KB [dk][kv], phi-swizzled
    __shared__ unsigned lut[NLUT];                  // 8 KB (v0, delta) bf16 pairs
    __shared__ float dbuf[128];                     // den exchange

    int tid = threadIdx.x, wave = tid >> 6, lane = tid & 63;
    int l31 = lane & 31, hi = lane >> 5;
    int wq = wave >> 1, st = wave & 1;
    int q0 = blockIdx.x * 64, bh = blockIdx.y;
    const short* Qp = Qb + (size_t)bh * S_LEN * DKH;
    const short* Kp = Kb + (size_t)bh * S_LEN * DKH;
    const short* Vp = VTb + (size_t)bh * DKH * S_LEN;

    #pragma unroll
    for (int i = tid; i < NLUT / 4; i += 256)
        ((uint4*)lut)[i] = ((const uint4*)lutg)[i];

    // Q as B-operand: lane supplies B[k=hi*8+j][q=l31] = Q[q0+wq*32+l31][k]
    bfx8 aq[4];
    #pragma unroll
    for (int ks = 0; ks < 4; ks++)
        aq[ks] = *(const bfx8*)(Qp + (size_t)(q0 + wq * 32 + l31) * DKH + ks * 16 + hi * 8);

    bfx8 ones;
    #pragma unroll
    for (int i = 0; i < 8; i++) ones[i] = (short)0x3F80;  // bf16 1.0

    fx16 oacc[2];
    fx16 dacc;
    #pragma unroll
    for (int r = 0; r < 16; r++) dacc[r] = 0.0f;
    #pragma unroll
    for (int dt = 0; dt < 2; dt++)
        #pragma unroll
        for (int r = 0; r < 16; r++) oacc[dt][r] = 0.0f;

    const float invh = (float)(NLUT - 1) / (LUT_MAX - LUT_MIN);
    const float xoff = -LUT_MIN * invh;

    // staging geometry: 512 slots of 16B per buffer, 2 per thread;
    // chunk swizzled by phi(row) = (row ^ (row>>3)) & 7
    int srow[2], sgc[2];
    #pragma unroll
    for (int r = 0; r < 2; r++) {
        int slot = (wave * 2 + r) * 64 + lane;
        srow[r] = slot >> 3;
        sgc[r] = (slot & 7) ^ ((srow[r] ^ (srow[r] >> 3)) & 7);
    }

    int krow = st * 32 + l31;
    int kphi = (krow ^ (krow >> 3)) & 7;

    for (int t0 = 0; t0 < S_LEN; t0 += 64) {
        __syncthreads();                 // all waves done reading tile t0-64
        #pragma unroll
        for (int r = 0; r < 2; r++) {
            gload_lds16(Kp + (size_t)(t0 + srow[r]) * DKH + sgc[r] * 8,
                        &Ks[((wave * 2 + r) * 64) * 8]);
            gload_lds16(Vp + (size_t)srow[r] * S_LEN + t0 + sgc[r] * 8,
                        &Vs[((wave * 2 + r) * 64) * 8]);
        }
        __syncthreads();                 // staging complete

        // S^T[kv32 (this wave's half)][q32] = K . Q^T over dk=64 (4 k-steps)
        fx16 sac;
        #pragma unroll
        for (int r = 0; r < 16; r++) sac[r] = 0.0f;
        #pragma unroll
        for (int ks = 0; ks < 4; ks++) {
            bfx8 kf = *(const bfx8*)(&Ks[krow * 64 + (((ks * 2 + hi) ^ kphi) * 8)]);
            sac = __builtin_amdgcn_mfma_f32_32x32x16_bf16(kf, aq[ks], sac, 0, 0, 0);
        }

        // p = g(s): one b32 (v0, delta) gather + fma lerp; pack pairs to bf16
        unsigned w[8];
        #pragma unroll
        for (int t = 0; t < 8; t++) {
            float pv[2];
            #pragma unroll
            for (int u = 0; u < 2; u++) {
                float s = sac[t * 2 + u];
                float x = fmaf(s, invh, xoff);
                x = __builtin_amdgcn_fmed3f(x, 0.0f, (float)(NLUT - 1));
                int j = (int)x;
                float f = x - (float)j;
                unsigned pr = lut[j];
                float v0 = __builtin_bit_cast(float, pr << 16);
                float dl = __builtin_bit_cast(float, pr & 0xffff0000u);
                pv[u] = fmaf(f, dl, v0);
            }
            w[t] = cvt_pk_bf16(pv[0], pv[1]);
        }

        // redistribute across lane halves -> PV B-fragments
        plane_swap(w[0], w[2]); plane_swap(w[1], w[3]);
        plane_swap(w[4], w[6]); plane_swap(w[5], w[7]);
        ux4 b0v = {w[0], w[1], w[2], w[3]};
        ux4 b1v = {w[4], w[5], w[6], w[7]};
        bfx8 pb0 = __builtin_bit_cast(bfx8, b0v);
        bfx8 pb1 = __builtin_bit_cast(bfx8, b1v);

        // O^T[dk][q] += VT . P^T   (2 dk-tiles x 2 k-steps)
        #pragma unroll
        for (int dt = 0; dt < 2; dt++) {
            int row = dt * 32 + l31;
            int vphi = (row ^ (row >> 3)) & 7;
            bfx8 v0f = *(const bfx8*)(&Vs[row * 64 + (((st * 4 + 0 + hi) ^ vphi) * 8)]);
            bfx8 v1f = *(const bfx8*)(&Vs[row * 64 + (((st * 4 + 2 + hi) ^ vphi) * 8)]);
            oacc[dt] = __builtin_amdgcn_mfma_f32_32x32x16_bf16(v0f, pb0, oacc[dt], 0, 0, 0);
            oacc[dt] = __builtin_amdgcn_mfma_f32_32x32x16_bf16(v1f, pb1, oacc[dt], 0, 0, 0);
        }
        // den[q] += sum_kv P[kv][q] on the matrix pipe (rows all equal)
        dacc = __builtin_amdgcn_mfma_f32_32x32x16_bf16(ones, pb0, dacc, 0, 0, 0);
        dacc = __builtin_amdgcn_mfma_f32_32x32x16_bf16(ones, pb1, dacc, 0, 0, 0);
    }

    float den = dacc[0];   // den[q=l31] for this wave's kv-half (rows equal)

    // combine kv halves: st=1 waves stash to LDS (Ks/Vs dead), st=0 finalize
    __syncthreads();
    float* obuf = (wq == 0) ? (float*)Ks : (float*)Vs;   // 8 KB each
    if (st == 1) {
        #pragma unroll
        for (int dt = 0; dt < 2; dt++)
            #pragma unroll
            for (int r = 0; r < 16; r++)
                obuf[(dt * 16 + r) * 64 + lane] = oacc[dt][r];
        dbuf[wq * 64 + lane] = den;
    }
    __syncthreads();
    if (st == 0) {
        float dtot = den + dbuf[wq * 64 + lane];
        int b = bh >> 4, h = bh & 15;
        #pragma unroll
        for (int dt = 0; dt < 2; dt++) {
            #pragma unroll
            for (int r = 0; r < 16; r++) {
                float o = oacc[dt][r] + obuf[(dt * 16 + r) * 64 + lane];
                int dk = dt * 32 + (r & 3) + 8 * (r >> 2) + 4 * hi;
                int q = q0 + wq * 32 + l31;
                AO[((size_t)(b * S_LEN + q)) * DMODEL + h * DKH + dk] = f2bf(o / dtot);
            }
        }
    }
}

// ---------------------------------------------------------------------------
extern "C" void kernel_launch(void* const* d_in, const int* in_sizes, int n_in,
                              void* d_out, int out_size, void* d_ws, size_t ws_size,
                              hipStream_t stream) {
    const float* query   = (const float*)d_in[0];
    const float* key_in  = (const float*)d_in[1];
    const float* value   = (const float*)d_in[2];
    const float* w_q     = (const float*)d_in[3];
    const float* b_q     = (const float*)d_in[4];
    const float* w_k     = (const float*)d_in[5];
    const float* b_k     = (const float*)d_in[6];
    const float* w_v     = (const float*)d_in[7];
    const float* b_v     = (const float*)d_in[8];
    const float* w_o     = (const float*)d_in[9];
    const float* b_o     = (const float*)d_in[10];
    const float* centers = (const float*)d_in[11];
    const float* widths  = (const float*)d_in[12];
    const float* temp    = (const float*)d_in[13];

    char* p = (char*)d_ws;
    auto alloc = [&](size_t bytes) -> void* {
        void* r = (void*)p;
        p += (bytes + 255) & ~(size_t)255;
        return r;
    };
    const size_t nBHSD = (size_t)2 * NHEAD * S_LEN * DKH;    // 4.19M elems
    const size_t nW    = (size_t)DMODEL * DMODEL;            // 1.05M elems
    unsigned* lutp = (unsigned*)alloc(NLUT * 4);
    short* Qb  = (short*)alloc(nBHSD * 2);
    short* Kb  = (short*)alloc(nBHSD * 2);
    short* VTb = (short*)alloc(nBHSD * 2);

    char* save = p;
    short* xq  = (short*)alloc(nBHSD * 2);
    short* xk  = (short*)alloc(nBHSD * 2);
    short* xv  = (short*)alloc(nBHSD * 2);
    short* bwq = (short*)alloc(nW * 2);
    short* bwk = (short*)alloc(nW * 2);
    short* bwv = (short*)alloc(nW * 2);
    short* bwo = (short*)alloc(nW * 2);
    bool fused = ((size_t)(p - (char*)d_ws) <= ws_size);

    dim3 blk(256), blk2(512);
    dim3 fg(32, 32);
    GemmJob JO;

    if (fused) {
        short* AO = xq;   // alias: xq dead after QKV gemm
        prep_all<<<dim3(1032), blk, 0, stream>>>(query, key_in, value, w_q, w_k, w_v, w_o,
                xq, xk, xv, bwq, bwk, bwv, bwo, centers, widths, temp, lutp);
        GemmJob JQ = {xq, bwq, b_q, Qb,  nullptr, 0, 0.125f};   // 1/sqrt(64) folded
        GemmJob JK = {xk, bwk, b_k, Kb,  nullptr, 0, 1.0f};
        GemmJob JV = {xv, bwv, b_v, VTb, nullptr, 1, 1.0f};
        gemm256<<<dim3(192), blk2, 0, stream>>>(JQ, JK, JV);
        flash_fuzzy<<<fg, blk, 0, stream>>>(Qb, Kb, VTb, lutp, AO);
        JO = {AO, bwo, b_o, nullptr, (float*)d_out, 2, 1.0f};
        gemm256<<<dim3(64), blk2, 0, stream>>>(JO, JO, JO);
    } else {
        // serial fallback: reuse one x-buffer + one w-buffer (~36 MB total)
        p = save;
        short* xf = (short*)alloc(nBHSD * 2);
        short* wb = (short*)alloc(nW * 2);
        short* AO = xf;
        const int n8x = (int)(nBHSD / 8), n8w = (int)(nW / 8);
        dim3 cg((n8x + 255) / 256), cw((n8w + 255) / 256);
        build_lut_pk<<<dim3(8), blk, 0, stream>>>(centers, widths, temp, lutp);
        cast_bf16<<<cg, blk, 0, stream>>>(query, xf, n8x);
        cast_bf16<<<cw, blk, 0, stream>>>(w_q, wb, n8w);
        JO = {xf, wb, b_q, Qb, nullptr, 0, 0.125f};
        gemm256<<<dim3(64), blk2, 0, stream>>>(JO, JO, JO);
        cast_bf16<<<cg, blk, 0, stream>>>(key_in, xf, n8x);
        cast_bf16<<<cw, blk, 0, stream>>>(w_k, wb, n8w);
        JO = {xf, wb, b_k, Kb, nullptr, 0, 1.0f};
        gemm256<<<dim3(64), blk2, 0, stream>>>(JO, JO, JO);
        cast_bf16<<<cg, blk, 0, stream>>>(value, xf, n8x);
        cast_bf16<<<cw, blk, 0, stream>>>(w_v, wb, n8w);
        JO = {xf, wb, b_v, VTb, nullptr, 1, 1.0f};
        gemm256<<<dim3(64), blk2, 0, stream>>>(JO, JO, JO);
        flash_fuzzy<<<fg, blk, 0, stream>>>(Qb, Kb, VTb, lutp, AO);
        cast_bf16<<<cw, blk, 0, stream>>>(w_o, wb, n8w);
        JO = {AO, wb, b_o, nullptr, (float*)d_out, 2, 1.0f};
        gemm256<<<dim3(64), blk2, 0, stream>>>(JO, JO, JO);
    }
}

// Round 12
// 273.494 us; speedup vs baseline: 1.0869x; 1.0832x over previous
//
#include <hip/hip_runtime.h>
#include <hip/hip_bf16.h>

// SimpleFuzzyAttention: B=2, S=2048, D=1024, H=16, DK=64
// fz(s) is univariate -> packed bf16 (v0, delta) LUT of g(s)=exp(fz(s)-bound);
// bound = 16/temp (analytic max of fz); constant cancels in softmax.
// R15: revert gemm256 (R13/R14: 512-thread block needs >=2 waves/EU, register
// cap spilled acc both times; ~100us/dispatch). Back to R11's gemm128
// (measured best total 259.9). ONE new lever: O-proj 2-way K-SPLIT in one
// dispatch -> 512 blocks = 2/CU (was 256 = 1/CU, no inter-block latency
// hiding). prep pre-fills d_out with bias; gemm mode 3 = atomicAdd f32.
// Flash/prep otherwise untouched from R11 (flash measured 75.1us).

#define S_LEN 2048
#define DMODEL 1024
#define NHEAD 16
#define DKH 64
#define NLUT 2048
#define LUT_MIN (-10.0f)
#define LUT_MAX (10.0f)

typedef __attribute__((ext_vector_type(8))) short bfx8;   // 8 bf16 (4 VGPRs)
typedef __attribute__((ext_vector_type(4))) float fx4;    // MFMA C/D 16x16
typedef __attribute__((ext_vector_type(16))) float fx16;  // MFMA C/D 32x32
typedef __attribute__((ext_vector_type(4))) unsigned ux4;

__device__ __forceinline__ short f2bf(float x) {
    unsigned u = __builtin_bit_cast(unsigned, x);
    u = (u + 0x7fffu + ((u >> 16) & 1u)) >> 16;   // RNE
    return (short)u;
}

__device__ __forceinline__ unsigned cvt_pk_bf16(float lo, float hi) {
    unsigned r;
    asm("v_cvt_pk_bf16_f32 %0, %1, %2" : "=v"(r) : "v"(lo), "v"(hi));
    return r;
}

// v_permlane32_swap_b32: after, a = {a_lo, b_lo}, b = {a_hi, b_hi}.
__device__ __forceinline__ void plane_swap(unsigned& a, unsigned& b) {
    asm volatile("v_permlane32_swap_b32 %0, %1" : "+v"(a), "+v"(b));
}

__device__ __forceinline__ void stage8_f32(const float* __restrict__ src, short* dst) {
    float4 a = *(const float4*)(src);
    float4 b = *(const float4*)(src + 4);
    bfx8 r;
    r[0] = f2bf(a.x); r[1] = f2bf(a.y); r[2] = f2bf(a.z); r[3] = f2bf(a.w);
    r[4] = f2bf(b.x); r[5] = f2bf(b.y); r[6] = f2bf(b.z); r[7] = f2bf(b.w);
    *(bfx8*)dst = r;
}

// global -> LDS direct 16B copy (LDS base wave-uniform; lane*16 implied)
__device__ __forceinline__ void gload_lds16(const void* g, void* l) {
    __builtin_amdgcn_global_load_lds(
        (const __attribute__((address_space(1))) unsigned int*)g,
        (__attribute__((address_space(3))) unsigned int*)l, 16, 0, 0);
}

// ---------------------------------------------------------------------------
// Parallel LUT slice: 8 blocks x 256 points. lutp[j] = bf16(g[j]) |
// bf16(g[j+1]-g[j])<<16, g = exp(fz - 16/temp). No division, no reduction.
// ---------------------------------------------------------------------------
__device__ void lut_slice(const float* __restrict__ centers, const float* __restrict__ widths,
                          const float* __restrict__ temp, unsigned* __restrict__ lutp,
                          int slice) {
    __shared__ float cs[48], iw[48];
    __shared__ float gsh[257];
    int tid = threadIdx.x;
    if (tid < 48) {
        cs[tid] = centers[tid];
        float w = widths[tid];
        iw[tid] = -0.5f / (w * w);
    }
    __syncthreads();
    float invT = 1.0f / temp[0];
    const float step = (LUT_MAX - LUT_MIN) / (float)(NLUT - 1);
    float bound = 16.0f * invT;
    int base = slice * 256;
    #pragma unroll 1
    for (int idx = tid; idx < 257; idx += 256) {   // tid 0 also does the halo
        int i = base + idx; if (i > NLUT - 1) i = NLUT - 1;
        float s = LUT_MIN + step * (float)i;
        float a = 0.0f;
        #pragma unroll
        for (int j = 0; j < 48; j++) {
            float d = s - cs[j];
            a += expf(d * d * iw[j]);
        }
        float fz = a * (1.0f / 3.0f) * invT;
        gsh[idx] = expf(fz - bound);
    }
    __syncthreads();
    float g0 = gsh[tid];
    unsigned lo = (unsigned short)f2bf(g0);
    unsigned hi = (unsigned short)f2bf(gsh[tid + 1] - g0);
    lutp[base + tid] = lo | (hi << 16);
}

__global__ void build_lut_pk(const float* centers, const float* widths,
                             const float* temp, unsigned* lutp) {
    lut_slice(centers, widths, temp, lutp, blockIdx.x);
}

// ---------------------------------------------------------------------------
// fp32 -> bf16 cast (fallback path), 8 elems/thread
// ---------------------------------------------------------------------------
__global__ void cast_bf16(const float* __restrict__ src, short* __restrict__ dst, int n8) {
    int i = blockIdx.x * 256 + threadIdx.x;
    if (i < n8) stage8_f32(src + (size_t)i * 8, dst + (size_t)i * 8);
}

// ---------------------------------------------------------------------------
// Fused prep: grid 1032. Blocks [0,1024) grid-stride 10240 work units:
// [0,6144)=input copies, [6144,8192)=weight copies, [8192,10240)=bias-fill
// of d_out (out[m][n] = b_o[n], required by the K-split atomic O-proj).
// Blocks [1024,1032) build the LUT.
// ---------------------------------------------------------------------------
__global__ void prep_all(const float* q, const float* kin, const float* v,
        const float* wq, const float* wk, const float* wv, const float* wo,
        short* xq, short* xk, short* xv,
        short* bwq, short* bwk, short* bwv, short* bwo,
        const float* centers, const float* widths, const float* temp,
        unsigned* lutp, const float* bo, float* out) {
    int bid = blockIdx.x;
    if (bid >= 1024) {
        lut_slice(centers, widths, temp, lutp, bid - 1024);
        return;
    }
    for (int vb = bid; vb < 10240; vb += 1024) {
        if (vb >= 8192) {
            // bias fill: unit covers 2048 f32 of out; 8 f32/thread, row-aligned
            size_t e = (size_t)(vb - 8192) * 2048 + threadIdx.x * 8;
            int n0 = (threadIdx.x * 8) & 1023;
            *(float4*)(out + e)     = *(const float4*)(bo + n0);
            *(float4*)(out + e + 4) = *(const float4*)(bo + n0 + 4);
            continue;
        }
        const float* src; short* dst; int blk;
        if (vb < 6144) {
            int y = vb >> 11; blk = vb & 2047;
            src = (y == 0) ? q : (y == 1) ? kin : v;
            dst = (y == 0) ? xq : (y == 1) ? xk : xv;
        } else {
            int y = (vb - 6144) >> 9; blk = (vb - 6144) & 511;
            src = (y == 0) ? wq : (y == 1) ? wk : (y == 2) ? wv : wo;
            dst = (y == 0) ? bwq : (y == 1) ? bwk : (y == 2) ? bwv : bwo;
        }
        size_t i = (size_t)blk * 256 + threadIdx.x;   // always in range (exact)
        stage8_f32(src + i * 8, (short*)dst + i * 8);
    }
}

// ---------------------------------------------------------------------------
// bf16 BT-GEMM, 128x128 tile, BK=32, double-buffered, launch_bounds(256,3).
// K-range [kb, ke) per job (K-split support).
// C[m,n] = (sum_k A[m,k]*W[n,k] + bias[n]) * scale.
// mode 0: bf16 [B,H,S,DK]; 1: bf16 [B,H,DK,S]; 2: fp32 [M,N] store;
// mode 3: fp32 [M,N] atomicAdd (dest pre-filled with bias; bv forced 0).
// ---------------------------------------------------------------------------
struct GemmJob {
    const short* A; const short* W; const float* bias;
    short* obf; float* of32; int mode; float scale; int kb; int ke;
};

__global__ __launch_bounds__(256, 3) void gemm128(GemmJob j0, GemmJob j1, GemmJob j2) {
    __shared__ __align__(16) short As[2][128 * 32];   // 2 x 8 KB, swizzled
    __shared__ __align__(16) short Bs[2][128 * 32];   // 2 x 8 KB
    GemmJob jb = (blockIdx.z == 0) ? j0 : (blockIdx.z == 1) ? j1 : j2;
    int tid = threadIdx.x, wave = tid >> 6, lane = tid & 63, quad = lane >> 4, l15 = lane & 15;
    int m0 = blockIdx.y * 128, n0 = blockIdx.x * 128;
    int wm = (wave >> 1) * 64, wn = (wave & 1) * 64;

    fx4 acc[4][4];
    #pragma unroll
    for (int i = 0; i < 4; i++)
        #pragma unroll
        for (int j = 0; j < 4; j++)
            #pragma unroll
            for (int r = 0; r < 4; r++) acc[i][j][r] = 0.0f;

    int fc = (quad ^ ((l15 >> 1) & 3)) * 8;        // swizzled frag chunk (shorts)

    // staging lane geometry (constant): 512 slots of 16B per buffer
    int srow[2], sgc[2];
    #pragma unroll
    for (int r = 0; r < 2; r++) {
        int slot = r * 256 + wave * 64 + lane;     // -> 128 rows x 4 chunks
        srow[r] = slot >> 2;
        sgc[r] = (slot & 3) ^ ((srow[r] >> 1) & 3);
    }

    auto stage = [&](int k0, int buf) {
        #pragma unroll
        for (int r = 0; r < 2; r++) {
            gload_lds16(jb.A + (size_t)(m0 + srow[r]) * DMODEL + k0 + sgc[r] * 8,
                        &As[buf][(r * 256 + wave * 64) * 8]);
            gload_lds16(jb.W + (size_t)(n0 + srow[r]) * DMODEL + k0 + sgc[r] * 8,
                        &Bs[buf][(r * 256 + wave * 64) * 8]);
        }
    };

    stage(jb.kb, 0);
    __syncthreads();                 // vmcnt(0) drain of prologue stage
    int buf = 0;
    for (int k0 = jb.kb; k0 < jb.ke; k0 += 32) {
        if (k0 + 32 < jb.ke) stage(k0 + 32, buf ^ 1);   // prefetch next tile
        bfx8 af[4], bfr[4];
        #pragma unroll
        for (int i = 0; i < 4; i++) af[i] = *(const bfx8*)(&As[buf][(wm + i * 16 + l15) * 32 + fc]);
        #pragma unroll
        for (int j = 0; j < 4; j++) bfr[j] = *(const bfx8*)(&Bs[buf][(wn + j * 16 + l15) * 32 + fc]);
        #pragma unroll
        for (int i = 0; i < 4; i++)
            #pragma unroll
            for (int j = 0; j < 4; j++)
                acc[i][j] = __builtin_amdgcn_mfma_f32_16x16x32_bf16(af[i], bfr[j], acc[i][j], 0, 0, 0);
        __syncthreads();             // drains prefetch (had full compute to fly)
        buf ^= 1;
    }

    // epilogue: C/D layout col=lane&15 (n), row=quad*4+reg (m)
    #pragma unroll
    for (int j = 0; j < 4; j++) {
        int n = n0 + wn + j * 16 + l15;
        float bv = (jb.mode == 3) ? 0.0f : jb.bias[n];
        #pragma unroll
        for (int i = 0; i < 4; i++) {
            #pragma unroll
            for (int r = 0; r < 4; r++) {
                int m = m0 + wm + i * 16 + quad * 4 + r;
                float v = (acc[i][j][r] + bv) * jb.scale;
                if (jb.mode == 0) {
                    int b = m >> 11, s = m & 2047, h = n >> 6, dk = n & 63;
                    jb.obf[(((size_t)(b * NHEAD + h)) * S_LEN + s) * DKH + dk] = f2bf(v);
                } else if (jb.mode == 1) {
                    int b = m >> 11, s = m & 2047, h = n >> 6, dk = n & 63;
                    jb.obf[(((size_t)(b * NHEAD + h)) * DKH + dk) * S_LEN + s] = f2bf(v);
                } else if (jb.mode == 2) {
                    jb.of32[(size_t)m * DMODEL + n] = v;
                } else {
                    atomicAdd(&jb.of32[(size_t)m * DMODEL + n], v);
                }
            }
        }
    }
}

// ---------------------------------------------------------------------------
// Fuzzy flash attention, unchanged from R11 (measured 75.1 us): 32x32x16
// MFMA, in-register P; K/V staged in LDS with phi(r)=(r^(r>>3))&7 swizzle;
// single (v0,delta) LUT; den via ones-MFMA; launch_bounds(256,4) — do NOT
// raise (R10: forcing 6 waves/EU spilled accumulators, 2.5x regression).
// ---------------------------------------------------------------------------
__global__ __launch_bounds__(256, 4) void flash_fuzzy(const short* __restrict__ Qb,
        const short* __restrict__ Kb, const short* __restrict__ VTb,
        const unsigned* __restrict__ lutg, short* __restrict__ AO) {
    __shared__ __align__(16) short Ks[64 * 64];     // 8 KB [kv][dk], phi-swizzled
    __shared__ __align__(16) short Vs[64 * 64];     // 8 KB [dk][kv], phi-swizzled
    __shared__ unsigned lut[NLUT];                  // 8 KB (v0, delta) bf16 pairs
    __shared__ float dbuf[128];                     // den exchange

    int tid = threadIdx.x, wave = tid >> 6, lane = tid & 63;
    int l31 = lane & 31, hi = lane >> 5;
    int wq = wave >> 1, st = wave & 1;
    int q0 = blockIdx.x * 64, bh = blockIdx.y;
    const short* Qp = Qb + (size_t)bh * S_LEN * DKH;
    const short* Kp = Kb + (size_t)bh * S_LEN * DKH;
    const short* Vp = VTb + (size_t)bh * DKH * S_LEN;

    #pragma unroll
    for (int i = tid; i < NLUT / 4; i += 256)
        ((uint4*)lut)[i] = ((const uint4*)lutg)[i];

    // Q as B-operand: lane supplies B[k=hi*8+j][q=l31] = Q[q0+wq*32+l31][k]
    bfx8 aq[4];
    #pragma unroll
    for (int ks = 0; ks < 4; ks++)
        aq[ks] = *(const bfx8*)(Qp + (size_t)(q0 + wq * 32 + l31) * DKH + ks * 16 + hi * 8);

    bfx8 ones;
    #pragma unroll
    for (int i = 0; i < 8; i++) ones[i] = (short)0x3F80;  // bf16 1.0

    fx16 oacc[2];
    fx16 dacc;
    #pragma unroll
    for (int r = 0; r < 16; r++) dacc[r] = 0.0f;
    #pragma unroll
    for (int dt = 0; dt < 2; dt++)
        #pragma unroll
        for (int r = 0; r < 16; r++) oacc[dt][r] = 0.0f;

    const float invh = (float)(NLUT - 1) / (LUT_MAX - LUT_MIN);
    const float xoff = -LUT_MIN * invh;

    // staging geometry: 512 slots of 16B per buffer, 2 per thread;
    // chunk swizzled by phi(row) = (row ^ (row>>3)) & 7
    int srow[2], sgc[2];
    #pragma unroll
    for (int r = 0; r < 2; r++) {
        int slot = (wave * 2 + r) * 64 + lane;
        srow[r] = slot >> 3;
        sgc[r] = (slot & 7) ^ ((srow[r] ^ (srow[r] >> 3)) & 7);
    }

    int krow = st * 32 + l31;
    int kphi = (krow ^ (krow >> 3)) & 7;

    for (int t0 = 0; t0 < S_LEN; t0 += 64) {
        __syncthreads();                 // all waves done reading tile t0-64
        #pragma unroll
        for (int r = 0; r < 2; r++) {
            gload_lds16(Kp + (size_t)(t0 + srow[r]) * DKH + sgc[r] * 8,
                        &Ks[((wave * 2 + r) * 64) * 8]);
            gload_lds16(Vp + (size_t)srow[r] * S_LEN + t0 + sgc[r] * 8,
                        &Vs[((wave * 2 + r) * 64) * 8]);
        }
        __syncthreads();                 // staging complete

        // S^T[kv32 (this wave's half)][q32] = K . Q^T over dk=64 (4 k-steps)
        fx16 sac;
        #pragma unroll
        for (int r = 0; r < 16; r++) sac[r] = 0.0f;
        #pragma unroll
        for (int ks = 0; ks < 4; ks++) {
            bfx8 kf = *(const bfx8*)(&Ks[krow * 64 + (((ks * 2 + hi) ^ kphi) * 8)]);
            sac = __builtin_amdgcn_mfma_f32_32x32x16_bf16(kf, aq[ks], sac, 0, 0, 0);
        }

        // p = g(s): one b32 (v0, delta) gather + fma lerp; pack pairs to bf16
        unsigned w[8];
        #pragma unroll
        for (int t = 0; t < 8; t++) {
            float pv[2];
            #pragma unroll
            for (int u = 0; u < 2; u++) {
                float s = sac[t * 2 + u];
                float x = fmaf(s, invh, xoff);
                x = __builtin_amdgcn_fmed3f(x, 0.0f, (float)(NLUT - 1));
                int j = (int)x;
                float f = x - (float)j;
                unsigned pr = lut[j];
                float v0 = __builtin_bit_cast(float, pr << 16);
                float dl = __builtin_bit_cast(float, pr & 0xffff0000u);
                pv[u] = fmaf(f, dl, v0);
            }
            w[t] = cvt_pk_bf16(pv[0], pv[1]);
        }

        // redistribute across lane halves -> PV B-fragments
        plane_swap(w[0], w[2]); plane_swap(w[1], w[3]);
        plane_swap(w[4], w[6]); plane_swap(w[5], w[7]);
        ux4 b0v = {w[0], w[1], w[2], w[3]};
        ux4 b1v = {w[4], w[5], w[6], w[7]};
        bfx8 pb0 = __builtin_bit_cast(bfx8, b0v);
        bfx8 pb1 = __builtin_bit_cast(bfx8, b1v);

        // O^T[dk][q] += VT . P^T   (2 dk-tiles x 2 k-steps)
        #pragma unroll
        for (int dt = 0; dt < 2; dt++) {
            int row = dt * 32 + l31;
            int vphi = (row ^ (row >> 3)) & 7;
            bfx8 v0f = *(const bfx8*)(&Vs[row * 64 + (((st * 4 + 0 + hi) ^ vphi) * 8)]);
            bfx8 v1f = *(const bfx8*)(&Vs[row * 64 + (((st * 4 + 2 + hi) ^ vphi) * 8)]);
            oacc[dt] = __builtin_amdgcn_mfma_f32_32x32x16_bf16(v0f, pb0, oacc[dt], 0, 0, 0);
            oacc[dt] = __builtin_amdgcn_mfma_f32_32x32x16_bf16(v1f, pb1, oacc[dt], 0, 0, 0);
        }
        // den[q] += sum_kv P[kv][q] on the matrix pipe (rows all equal)
        dacc = __builtin_amdgcn_mfma_f32_32x32x16_bf16(ones, pb0, dacc, 0, 0, 0);
        dacc = __builtin_amdgcn_mfma_f32_32x32x16_bf16(ones, pb1, dacc, 0, 0, 0);
    }

    float den = dacc[0];   // den[q=l31] for this wave's kv-half (rows equal)

    // combine kv halves: st=1 waves stash to LDS (Ks/Vs dead), st=0 finalize
    __syncthreads();
    float* obuf = (wq == 0) ? (float*)Ks : (float*)Vs;   // 8 KB each
    if (st == 1) {
        #pragma unroll
        for (int dt = 0; dt < 2; dt++)
            #pragma unroll
            for (int r = 0; r < 16; r++)
                obuf[(dt * 16 + r) * 64 + lane] = oacc[dt][r];
        dbuf[wq * 64 + lane] = den;
    }
    __syncthreads();
    if (st == 0) {
        float dtot = den + dbuf[wq * 64 + lane];
        int b = bh >> 4, h = bh & 15;
        #pragma unroll
        for (int dt = 0; dt < 2; dt++) {
            #pragma unroll
            for (int r = 0; r < 16; r++) {
                float o = oacc[dt][r] + obuf[(dt * 16 + r) * 64 + lane];
                int dk = dt * 32 + (r & 3) + 8 * (r >> 2) + 4 * hi;
                int q = q0 + wq * 32 + l31;
                AO[((size_t)(b * S_LEN + q)) * DMODEL + h * DKH + dk] = f2bf(o / dtot);
            }
        }
    }
}

// ---------------------------------------------------------------------------
extern "C" void kernel_launch(void* const* d_in, const int* in_sizes, int n_in,
                              void* d_out, int out_size, void* d_ws, size_t ws_size,
                              hipStream_t stream) {
    const float* query   = (const float*)d_in[0];
    const float* key_in  = (const float*)d_in[1];
    const float* value   = (const float*)d_in[2];
    const float* w_q     = (const float*)d_in[3];
    const float* b_q     = (const float*)d_in[4];
    const float* w_k     = (const float*)d_in[5];
    const float* b_k     = (const float*)d_in[6];
    const float* w_v     = (const float*)d_in[7];
    const float* b_v     = (const float*)d_in[8];
    const float* w_o     = (const float*)d_in[9];
    const float* b_o     = (const float*)d_in[10];
    const float* centers = (const float*)d_in[11];
    const float* widths  = (const float*)d_in[12];
    const float* temp    = (const float*)d_in[13];

    char* p = (char*)d_ws;
    auto alloc = [&](size_t bytes) -> void* {
        void* r = (void*)p;
        p += (bytes + 255) & ~(size_t)255;
        return r;
    };
    const size_t nBHSD = (size_t)2 * NHEAD * S_LEN * DKH;    // 4.19M elems
    const size_t nW    = (size_t)DMODEL * DMODEL;            // 1.05M elems
    unsigned* lutp = (unsigned*)alloc(NLUT * 4);
    short* Qb  = (short*)alloc(nBHSD * 2);
    short* Kb  = (short*)alloc(nBHSD * 2);
    short* VTb = (short*)alloc(nBHSD * 2);

    char* save = p;
    short* xq  = (short*)alloc(nBHSD * 2);
    short* xk  = (short*)alloc(nBHSD * 2);
    short* xv  = (short*)alloc(nBHSD * 2);
    short* bwq = (short*)alloc(nW * 2);
    short* bwk = (short*)alloc(nW * 2);
    short* bwv = (short*)alloc(nW * 2);
    short* bwo = (short*)alloc(nW * 2);
    bool fused = ((size_t)(p - (char*)d_ws) <= ws_size);

    dim3 blk(256);
    dim3 gq(8, 32, 3), go(8, 32, 2), g1(8, 32, 1), fg(32, 32);
    GemmJob JO;

    if (fused) {
        short* AO = xq;   // alias: xq dead after QKV gemm
        prep_all<<<dim3(1032), blk, 0, stream>>>(query, key_in, value, w_q, w_k, w_v, w_o,
                xq, xk, xv, bwq, bwk, bwv, bwo, centers, widths, temp, lutp,
                b_o, (float*)d_out);
        GemmJob JQ = {xq, bwq, b_q, Qb,  nullptr, 0, 0.125f, 0, 1024};  // 1/sqrt(64)
        GemmJob JK = {xk, bwk, b_k, Kb,  nullptr, 0, 1.0f, 0, 1024};
        GemmJob JV = {xv, bwv, b_v, VTb, nullptr, 1, 1.0f, 0, 1024};
        gemm128<<<gq, blk, 0, stream>>>(JQ, JK, JV);
        flash_fuzzy<<<fg, blk, 0, stream>>>(Qb, Kb, VTb, lutp, AO);
        // O-proj: 2-way K-split, one dispatch (512 blocks = 2/CU); d_out
        // pre-filled with bias by prep_all; mode 3 = atomicAdd.
        GemmJob JO1 = {AO, bwo, b_o, nullptr, (float*)d_out, 3, 1.0f, 0, 512};
        GemmJob JO2 = {AO, bwo, b_o, nullptr, (float*)d_out, 3, 1.0f, 512, 1024};
        gemm128<<<go, blk, 0, stream>>>(JO1, JO2, JO1);
    } else {
        // serial fallback: reuse one x-buffer + one w-buffer (~36 MB total)
        p = save;
        short* xf = (short*)alloc(nBHSD * 2);
        short* wb = (short*)alloc(nW * 2);
        short* AO = xf;
        const int n8x = (int)(nBHSD / 8), n8w = (int)(nW / 8);
        dim3 cg((n8x + 255) / 256), cw((n8w + 255) / 256);
        build_lut_pk<<<dim3(8), blk, 0, stream>>>(centers, widths, temp, lutp);
        cast_bf16<<<cg, blk, 0, stream>>>(query, xf, n8x);
        cast_bf16<<<cw, blk, 0, stream>>>(w_q, wb, n8w);
        JO = {xf, wb, b_q, Qb, nullptr, 0, 0.125f, 0, 1024};
        gemm128<<<g1, blk, 0, stream>>>(JO, JO, JO);
        cast_bf16<<<cg, blk, 0, stream>>>(key_in, xf, n8x);
        cast_bf16<<<cw, blk, 0, stream>>>(w_k, wb, n8w);
        JO = {xf, wb, b_k, Kb, nullptr, 0, 1.0f, 0, 1024};
        gemm128<<<g1, blk, 0, stream>>>(JO, JO, JO);
        cast_bf16<<<cg, blk, 0, stream>>>(value, xf, n8x);
        cast_bf16<<<cw, blk, 0, stream>>>(w_v, wb, n8w);
        JO = {xf, wb, b_v, VTb, nullptr, 1, 1.0f, 0, 1024};
        gemm128<<<g1, blk, 0, stream>>>(JO, JO, JO);
        flash_fuzzy<<<fg, blk, 0, stream>>>(Qb, Kb, VTb, lutp, AO);
        cast_bf16<<<cw, blk, 0, stream>>>(w_o, wb, n8w);
        JO = {AO, wb, b_o, nullptr, (float*)d_out, 2, 1.0f, 0, 1024};
        gemm128<<<g1, blk, 0, stream>>>(JO, JO, JO);
    }
}

// Round 13
// 260.294 us; speedup vs baseline: 1.1420x; 1.0507x over previous
//
#include <hip/hip_runtime.h>
#include <hip/hip_bf16.h>

// SimpleFuzzyAttention: B=2, S=2048, D=1024, H=16, DK=64
// fz(s) is univariate -> packed bf16 (v0, delta) LUT of g(s)=exp(fz(s)-bound);
// bound = 16/temp (analytic max of fz); constant cancels in softmax.
// R16: restore measured-best R11 exactly (R15's K-split atomic O-proj cost
// +13.6us; R12/R13/R14 GEMM experiments all lost to plain gemm128 — the
// 128^2 2-barrier structure is at its expected shape-curve rate here).
// ONE safe flash trim on the dominant VALU pipe: j/f via v_cvt_i32 +
// v_fract_f32 (2 ops, was 3: cvt, cvt-back, sub) on the gather chain.

#define S_LEN 2048
#define DMODEL 1024
#define NHEAD 16
#define DKH 64
#define NLUT 2048
#define LUT_MIN (-10.0f)
#define LUT_MAX (10.0f)

typedef __attribute__((ext_vector_type(8))) short bfx8;   // 8 bf16 (4 VGPRs)
typedef __attribute__((ext_vector_type(4))) float fx4;    // MFMA C/D 16x16
typedef __attribute__((ext_vector_type(16))) float fx16;  // MFMA C/D 32x32
typedef __attribute__((ext_vector_type(4))) unsigned ux4;

__device__ __forceinline__ short f2bf(float x) {
    unsigned u = __builtin_bit_cast(unsigned, x);
    u = (u + 0x7fffu + ((u >> 16) & 1u)) >> 16;   // RNE
    return (short)u;
}

__device__ __forceinline__ unsigned cvt_pk_bf16(float lo, float hi) {
    unsigned r;
    asm("v_cvt_pk_bf16_f32 %0, %1, %2" : "=v"(r) : "v"(lo), "v"(hi));
    return r;
}

// v_permlane32_swap_b32: after, a = {a_lo, b_lo}, b = {a_hi, b_hi}.
__device__ __forceinline__ void plane_swap(unsigned& a, unsigned& b) {
    asm volatile("v_permlane32_swap_b32 %0, %1" : "+v"(a), "+v"(b));
}

__device__ __forceinline__ void stage8_f32(const float* __restrict__ src, short* dst) {
    float4 a = *(const float4*)(src);
    float4 b = *(const float4*)(src + 4);
    bfx8 r;
    r[0] = f2bf(a.x); r[1] = f2bf(a.y); r[2] = f2bf(a.z); r[3] = f2bf(a.w);
    r[4] = f2bf(b.x); r[5] = f2bf(b.y); r[6] = f2bf(b.z); r[7] = f2bf(b.w);
    *(bfx8*)dst = r;
}

// global -> LDS direct 16B copy (LDS base wave-uniform; lane*16 implied)
__device__ __forceinline__ void gload_lds16(const void* g, void* l) {
    __builtin_amdgcn_global_load_lds(
        (const __attribute__((address_space(1))) unsigned int*)g,
        (__attribute__((address_space(3))) unsigned int*)l, 16, 0, 0);
}

// ---------------------------------------------------------------------------
// Parallel LUT slice: 8 blocks x 256 points. lutp[j] = bf16(g[j]) |
// bf16(g[j+1]-g[j])<<16, g = exp(fz - 16/temp). No division, no reduction.
// ---------------------------------------------------------------------------
__device__ void lut_slice(const float* __restrict__ centers, const float* __restrict__ widths,
                          const float* __restrict__ temp, unsigned* __restrict__ lutp,
                          int slice) {
    __shared__ float cs[48], iw[48];
    __shared__ float gsh[257];
    int tid = threadIdx.x;
    if (tid < 48) {
        cs[tid] = centers[tid];
        float w = widths[tid];
        iw[tid] = -0.5f / (w * w);
    }
    __syncthreads();
    float invT = 1.0f / temp[0];
    const float step = (LUT_MAX - LUT_MIN) / (float)(NLUT - 1);
    float bound = 16.0f * invT;
    int base = slice * 256;
    #pragma unroll 1
    for (int idx = tid; idx < 257; idx += 256) {   // tid 0 also does the halo
        int i = base + idx; if (i > NLUT - 1) i = NLUT - 1;
        float s = LUT_MIN + step * (float)i;
        float a = 0.0f;
        #pragma unroll
        for (int j = 0; j < 48; j++) {
            float d = s - cs[j];
            a += expf(d * d * iw[j]);
        }
        float fz = a * (1.0f / 3.0f) * invT;
        gsh[idx] = expf(fz - bound);
    }
    __syncthreads();
    float g0 = gsh[tid];
    unsigned lo = (unsigned short)f2bf(g0);
    unsigned hi = (unsigned short)f2bf(gsh[tid + 1] - g0);
    lutp[base + tid] = lo | (hi << 16);
}

__global__ void build_lut_pk(const float* centers, const float* widths,
                             const float* temp, unsigned* lutp) {
    lut_slice(centers, widths, temp, lutp, blockIdx.x);
}

// ---------------------------------------------------------------------------
// fp32 -> bf16 cast (fallback path), 8 elems/thread
// ---------------------------------------------------------------------------
__global__ void cast_bf16(const float* __restrict__ src, short* __restrict__ dst, int n8) {
    int i = blockIdx.x * 256 + threadIdx.x;
    if (i < n8) stage8_f32(src + (size_t)i * 8, dst + (size_t)i * 8);
}

// ---------------------------------------------------------------------------
// Fused prep: grid 1032. Blocks [0,1024) grid-stride the 8192 copy units
// ([0,6144)=inputs, [6144,8192)=weights); blocks [1024,1032) build the LUT.
// ---------------------------------------------------------------------------
__global__ void prep_all(const float* q, const float* kin, const float* v,
        const float* wq, const float* wk, const float* wv, const float* wo,
        short* xq, short* xk, short* xv,
        short* bwq, short* bwk, short* bwv, short* bwo,
        const float* centers, const float* widths, const float* temp,
        unsigned* lutp) {
    int bid = blockIdx.x;
    if (bid >= 1024) {
        lut_slice(centers, widths, temp, lutp, bid - 1024);
        return;
    }
    for (int vb = bid; vb < 8192; vb += 1024) {
        const float* src; short* dst; int blk;
        if (vb < 6144) {
            int y = vb >> 11; blk = vb & 2047;
            src = (y == 0) ? q : (y == 1) ? kin : v;
            dst = (y == 0) ? xq : (y == 1) ? xk : xv;
        } else {
            int y = (vb - 6144) >> 9; blk = (vb - 6144) & 511;
            src = (y == 0) ? wq : (y == 1) ? wk : (y == 2) ? wv : wo;
            dst = (y == 0) ? bwq : (y == 1) ? bwk : (y == 2) ? bwv : bwo;
        }
        size_t i = (size_t)blk * 256 + threadIdx.x;   // always in range (exact)
        stage8_f32(src + i * 8, (short*)dst + i * 8);
    }
}

// ---------------------------------------------------------------------------
// bf16 BT-GEMM, 128x128 tile, BK=32, double-buffered, launch_bounds(256,3).
// C[m,n] = (sum_k A[m,k]*W[n,k] + bias[n]) * scale.
// mode 0: bf16 [B,H,S,DK]; 1: bf16 [B,H,DK,S]; 2: fp32 [M,N]
// ---------------------------------------------------------------------------
struct GemmJob {
    const short* A; const short* W; const float* bias;
    short* obf; float* of32; int mode; float scale;
};

__global__ __launch_bounds__(256, 3) void gemm128(GemmJob j0, GemmJob j1, GemmJob j2) {
    __shared__ __align__(16) short As[2][128 * 32];   // 2 x 8 KB, swizzled
    __shared__ __align__(16) short Bs[2][128 * 32];   // 2 x 8 KB
    GemmJob jb = (blockIdx.z == 0) ? j0 : (blockIdx.z == 1) ? j1 : j2;
    int tid = threadIdx.x, wave = tid >> 6, lane = tid & 63, quad = lane >> 4, l15 = lane & 15;
    int m0 = blockIdx.y * 128, n0 = blockIdx.x * 128;
    int wm = (wave >> 1) * 64, wn = (wave & 1) * 64;

    fx4 acc[4][4];
    #pragma unroll
    for (int i = 0; i < 4; i++)
        #pragma unroll
        for (int j = 0; j < 4; j++)
            #pragma unroll
            for (int r = 0; r < 4; r++) acc[i][j][r] = 0.0f;

    int fc = (quad ^ ((l15 >> 1) & 3)) * 8;        // swizzled frag chunk (shorts)

    // staging lane geometry (constant): 512 slots of 16B per buffer
    int srow[2], sgc[2];
    #pragma unroll
    for (int r = 0; r < 2; r++) {
        int slot = r * 256 + wave * 64 + lane;     // -> 128 rows x 4 chunks
        srow[r] = slot >> 2;
        sgc[r] = (slot & 3) ^ ((srow[r] >> 1) & 3);
    }

    auto stage = [&](int k0, int buf) {
        #pragma unroll
        for (int r = 0; r < 2; r++) {
            gload_lds16(jb.A + (size_t)(m0 + srow[r]) * DMODEL + k0 + sgc[r] * 8,
                        &As[buf][(r * 256 + wave * 64) * 8]);
            gload_lds16(jb.W + (size_t)(n0 + srow[r]) * DMODEL + k0 + sgc[r] * 8,
                        &Bs[buf][(r * 256 + wave * 64) * 8]);
        }
    };

    stage(0, 0);
    __syncthreads();                 // vmcnt(0) drain of prologue stage
    int buf = 0;
    for (int k0 = 0; k0 < DMODEL; k0 += 32) {
        if (k0 + 32 < DMODEL) stage(k0 + 32, buf ^ 1);   // prefetch next tile
        bfx8 af[4], bfr[4];
        #pragma unroll
        for (int i = 0; i < 4; i++) af[i] = *(const bfx8*)(&As[buf][(wm + i * 16 + l15) * 32 + fc]);
        #pragma unroll
        for (int j = 0; j < 4; j++) bfr[j] = *(const bfx8*)(&Bs[buf][(wn + j * 16 + l15) * 32 + fc]);
        #pragma unroll
        for (int i = 0; i < 4; i++)
            #pragma unroll
            for (int j = 0; j < 4; j++)
                acc[i][j] = __builtin_amdgcn_mfma_f32_16x16x32_bf16(af[i], bfr[j], acc[i][j], 0, 0, 0);
        __syncthreads();             // drains prefetch (had full compute to fly)
        buf ^= 1;
    }

    // epilogue: C/D layout col=lane&15 (n), row=quad*4+reg (m)
    #pragma unroll
    for (int j = 0; j < 4; j++) {
        int n = n0 + wn + j * 16 + l15;
        float bv = jb.bias[n];
        #pragma unroll
        for (int i = 0; i < 4; i++) {
            #pragma unroll
            for (int r = 0; r < 4; r++) {
                int m = m0 + wm + i * 16 + quad * 4 + r;
                float v = (acc[i][j][r] + bv) * jb.scale;
                if (jb.mode == 0) {
                    int b = m >> 11, s = m & 2047, h = n >> 6, dk = n & 63;
                    jb.obf[(((size_t)(b * NHEAD + h)) * S_LEN + s) * DKH + dk] = f2bf(v);
                } else if (jb.mode == 1) {
                    int b = m >> 11, s = m & 2047, h = n >> 6, dk = n & 63;
                    jb.obf[(((size_t)(b * NHEAD + h)) * DKH + dk) * S_LEN + s] = f2bf(v);
                } else {
                    jb.of32[(size_t)m * DMODEL + n] = v;
                }
            }
        }
    }
}

// ---------------------------------------------------------------------------
// Fuzzy flash attention, R11 structure (measured 75.1 us) + fract trim:
// 32x32x16 MFMA, in-register P; K/V staged in LDS with phi(r)=(r^(r>>3))&7
// swizzle; single (v0,delta) LUT; den via ones-MFMA; launch_bounds(256,4) —
// do NOT raise (R10: forcing 6 waves/EU spilled accumulators, 2.5x regr.).
// Gather chain: j = v_cvt_i32(x), f = v_fract(x)  (was 3 ops, now 2).
// ---------------------------------------------------------------------------
__global__ __launch_bounds__(256, 4) void flash_fuzzy(const short* __restrict__ Qb,
        const short* __restrict__ Kb, const short* __restrict__ VTb,
        const unsigned* __restrict__ lutg, short* __restrict__ AO) {
    __shared__ __align__(16) short Ks[64 * 64];     // 8 KB [kv][dk], phi-swizzled
    __shared__ __align__(16) short Vs[64 * 64];     // 8 KB [dk][kv], phi-swizzled
    __shared__ unsigned lut[NLUT];                  // 8 KB (v0, delta) bf16 pairs
    __shared__ float dbuf[128];                     // den exchange

    int tid = threadIdx.x, wave = tid >> 6, lane = tid & 63;
    int l31 = lane & 31, hi = lane >> 5;
    int wq = wave >> 1, st = wave & 1;
    int q0 = blockIdx.x * 64, bh = blockIdx.y;
    const short* Qp = Qb + (size_t)bh * S_LEN * DKH;
    const short* Kp = Kb + (size_t)bh * S_LEN * DKH;
    const short* Vp = VTb + (size_t)bh * DKH * S_LEN;

    #pragma unroll
    for (int i = tid; i < NLUT / 4; i += 256)
        ((uint4*)lut)[i] = ((const uint4*)lutg)[i];

    // Q as B-operand: lane supplies B[k=hi*8+j][q=l31] = Q[q0+wq*32+l31][k]
    bfx8 aq[4];
    #pragma unroll
    for (int ks = 0; ks < 4; ks++)
        aq[ks] = *(const bfx8*)(Qp + (size_t)(q0 + wq * 32 + l31) * DKH + ks * 16 + hi * 8);

    bfx8 ones;
    #pragma unroll
    for (int i = 0; i < 8; i++) ones[i] = (short)0x3F80;  // bf16 1.0

    fx16 oacc[2];
    fx16 dacc;
    #pragma unroll
    for (int r = 0; r < 16; r++) dacc[r] = 0.0f;
    #pragma unroll
    for (int dt = 0; dt < 2; dt++)
        #pragma unroll
        for (int r = 0; r < 16; r++) oacc[dt][r] = 0.0f;

    const float invh = (float)(NLUT - 1) / (LUT_MAX - LUT_MIN);
    const float xoff = -LUT_MIN * invh;

    // staging geometry: 512 slots of 16B per buffer, 2 per thread;
    // chunk swizzled by phi(row) = (row ^ (row>>3)) & 7
    int srow[2], sgc[2];
    #pragma unroll
    for (int r = 0; r < 2; r++) {
        int slot = (wave * 2 + r) * 64 + lane;
        srow[r] = slot >> 3;
        sgc[r] = (slot & 7) ^ ((srow[r] ^ (srow[r] >> 3)) & 7);
    }

    int krow = st * 32 + l31;
    int kphi = (krow ^ (krow >> 3)) & 7;

    for (int t0 = 0; t0 < S_LEN; t0 += 64) {
        __syncthreads();                 // all waves done reading tile t0-64
        #pragma unroll
        for (int r = 0; r < 2; r++) {
            gload_lds16(Kp + (size_t)(t0 + srow[r]) * DKH + sgc[r] * 8,
                        &Ks[((wave * 2 + r) * 64) * 8]);
            gload_lds16(Vp + (size_t)srow[r] * S_LEN + t0 + sgc[r] * 8,
                        &Vs[((wave * 2 + r) * 64) * 8]);
        }
        __syncthreads();                 // staging complete

        // S^T[kv32 (this wave's half)][q32] = K . Q^T over dk=64 (4 k-steps)
        fx16 sac;
        #pragma unroll
        for (int r = 0; r < 16; r++) sac[r] = 0.0f;
        #pragma unroll
        for (int ks = 0; ks < 4; ks++) {
            bfx8 kf = *(const bfx8*)(&Ks[krow * 64 + (((ks * 2 + hi) ^ kphi) * 8)]);
            sac = __builtin_amdgcn_mfma_f32_32x32x16_bf16(kf, aq[ks], sac, 0, 0, 0);
        }

        // p = g(s): one b32 (v0, delta) gather + fma lerp; pack pairs to bf16
        unsigned w[8];
        #pragma unroll
        for (int t = 0; t < 8; t++) {
            float pv[2];
            #pragma unroll
            for (int u = 0; u < 2; u++) {
                float s = sac[t * 2 + u];
                float x = fmaf(s, invh, xoff);
                x = __builtin_amdgcn_fmed3f(x, 0.0f, (float)(NLUT - 1));
                int j = (int)x;                          // v_cvt_i32_f32
                float f = __builtin_amdgcn_fractf(x);    // v_fract_f32 (x>=0)
                unsigned pr = lut[j];
                float v0 = __builtin_bit_cast(float, pr << 16);
                float dl = __builtin_bit_cast(float, pr & 0xffff0000u);
                pv[u] = fmaf(f, dl, v0);
            }
            w[t] = cvt_pk_bf16(pv[0], pv[1]);
        }

        // redistribute across lane halves -> PV B-fragments
        plane_swap(w[0], w[2]); plane_swap(w[1], w[3]);
        plane_swap(w[4], w[6]); plane_swap(w[5], w[7]);
        ux4 b0v = {w[0], w[1], w[2], w[3]};
        ux4 b1v = {w[4], w[5], w[6], w[7]};
        bfx8 pb0 = __builtin_bit_cast(bfx8, b0v);
        bfx8 pb1 = __builtin_bit_cast(bfx8, b1v);

        // O^T[dk][q] += VT . P^T   (2 dk-tiles x 2 k-steps)
        #pragma unroll
        for (int dt = 0; dt < 2; dt++) {
            int row = dt * 32 + l31;
            int vphi = (row ^ (row >> 3)) & 7;
            bfx8 v0f = *(const bfx8*)(&Vs[row * 64 + (((st * 4 + 0 + hi) ^ vphi) * 8)]);
            bfx8 v1f = *(const bfx8*)(&Vs[row * 64 + (((st * 4 + 2 + hi) ^ vphi) * 8)]);
            oacc[dt] = __builtin_amdgcn_mfma_f32_32x32x16_bf16(v0f, pb0, oacc[dt], 0, 0, 0);
            oacc[dt] = __builtin_amdgcn_mfma_f32_32x32x16_bf16(v1f, pb1, oacc[dt], 0, 0, 0);
        }
        // den[q] += sum_kv P[kv][q] on the matrix pipe (rows all equal)
        dacc = __builtin_amdgcn_mfma_f32_32x32x16_bf16(ones, pb0, dacc, 0, 0, 0);
        dacc = __builtin_amdgcn_mfma_f32_32x32x16_bf16(ones, pb1, dacc, 0, 0, 0);
    }

    float den = dacc[0];   // den[q=l31] for this wave's kv-half (rows equal)

    // combine kv halves: st=1 waves stash to LDS (Ks/Vs dead), st=0 finalize
    __syncthreads();
    float* obuf = (wq == 0) ? (float*)Ks : (float*)Vs;   // 8 KB each
    if (st == 1) {
        #pragma unroll
        for (int dt = 0; dt < 2; dt++)
            #pragma unroll
            for (int r = 0; r < 16; r++)
                obuf[(dt * 16 + r) * 64 + lane] = oacc[dt][r];
        dbuf[wq * 64 + lane] = den;
    }
    __syncthreads();
    if (st == 0) {
        float dtot = den + dbuf[wq * 64 + lane];
        int b = bh >> 4, h = bh & 15;
        #pragma unroll
        for (int dt = 0; dt < 2; dt++) {
            #pragma unroll
            for (int r = 0; r < 16; r++) {
                float o = oacc[dt][r] + obuf[(dt * 16 + r) * 64 + lane];
                int dk = dt * 32 + (r & 3) + 8 * (r >> 2) + 4 * hi;
                int q = q0 + wq * 32 + l31;
                AO[((size_t)(b * S_LEN + q)) * DMODEL + h * DKH + dk] = f2bf(o / dtot);
            }
        }
    }
}

// ---------------------------------------------------------------------------
extern "C" void kernel_launch(void* const* d_in, const int* in_sizes, int n_in,
                              void* d_out, int out_size, void* d_ws, size_t ws_size,
                              hipStream_t stream) {
    const float* query   = (const float*)d_in[0];
    const float* key_in  = (const float*)d_in[1];
    const float* value   = (const float*)d_in[2];
    const float* w_q     = (const float*)d_in[3];
    const float* b_q     = (const float*)d_in[4];
    const float* w_k     = (const float*)d_in[5];
    const float* b_k     = (const float*)d_in[6];
    const float* w_v     = (const float*)d_in[7];
    const float* b_v     = (const float*)d_in[8];
    const float* w_o     = (const float*)d_in[9];
    const float* b_o     = (const float*)d_in[10];
    const float* centers = (const float*)d_in[11];
    const float* widths  = (const float*)d_in[12];
    const float* temp    = (const float*)d_in[13];

    char* p = (char*)d_ws;
    auto alloc = [&](size_t bytes) -> void* {
        void* r = (void*)p;
        p += (bytes + 255) & ~(size_t)255;
        return r;
    };
    const size_t nBHSD = (size_t)2 * NHEAD * S_LEN * DKH;    // 4.19M elems
    const size_t nW    = (size_t)DMODEL * DMODEL;            // 1.05M elems
    unsigned* lutp = (unsigned*)alloc(NLUT * 4);
    short* Qb  = (short*)alloc(nBHSD * 2);
    short* Kb  = (short*)alloc(nBHSD * 2);
    short* VTb = (short*)alloc(nBHSD * 2);

    char* save = p;
    short* xq  = (short*)alloc(nBHSD * 2);
    short* xk  = (short*)alloc(nBHSD * 2);
    short* xv  = (short*)alloc(nBHSD * 2);
    short* bwq = (short*)alloc(nW * 2);
    short* bwk = (short*)alloc(nW * 2);
    short* bwv = (short*)alloc(nW * 2);
    short* bwo = (short*)alloc(nW * 2);
    bool fused = ((size_t)(p - (char*)d_ws) <= ws_size);

    dim3 blk(256);
    dim3 gq(8, 32, 3), g1(8, 32, 1), fg(32, 32);
    GemmJob JO;

    if (fused) {
        short* AO = xq;   // alias: xq dead after QKV gemm
        prep_all<<<dim3(1032), blk, 0, stream>>>(query, key_in, value, w_q, w_k, w_v, w_o,
                xq, xk, xv, bwq, bwk, bwv, bwo, centers, widths, temp, lutp);
        GemmJob JQ = {xq, bwq, b_q, Qb,  nullptr, 0, 0.125f};   // 1/sqrt(64) folded
        GemmJob JK = {xk, bwk, b_k, Kb,  nullptr, 0, 1.0f};
        GemmJob JV = {xv, bwv, b_v, VTb, nullptr, 1, 1.0f};
        gemm128<<<gq, blk, 0, stream>>>(JQ, JK, JV);
        flash_fuzzy<<<fg, blk, 0, stream>>>(Qb, Kb, VTb, lutp, AO);
        JO = {AO, bwo, b_o, nullptr, (float*)d_out, 2, 1.0f};
        gemm128<<<g1, blk, 0, stream>>>(JO, JO, JO);
    } else {
        // serial fallback: reuse one x-buffer + one w-buffer (~36 MB total)
        p = save;
        short* xf = (short*)alloc(nBHSD * 2);
        short* wb = (short*)alloc(nW * 2);
        short* AO = xf;
        const int n8x = (int)(nBHSD / 8), n8w = (int)(nW / 8);
        dim3 cg((n8x + 255) / 256), cw((n8w + 255) / 256);
        build_lut_pk<<<dim3(8), blk, 0, stream>>>(centers, widths, temp, lutp);
        cast_bf16<<<cg, blk, 0, stream>>>(query, xf, n8x);
        cast_bf16<<<cw, blk, 0, stream>>>(w_q, wb, n8w);
        JO = {xf, wb, b_q, Qb, nullptr, 0, 0.125f};
        gemm128<<<g1, blk, 0, stream>>>(JO, JO, JO);
        cast_bf16<<<cg, blk, 0, stream>>>(key_in, xf, n8x);
        cast_bf16<<<cw, blk, 0, stream>>>(w_k, wb, n8w);
        JO = {xf, wb, b_k, Kb, nullptr, 0, 1.0f};
        gemm128<<<g1, blk, 0, stream>>>(JO, JO, JO);
        cast_bf16<<<cg, blk, 0, stream>>>(value, xf, n8x);
        cast_bf16<<<cw, blk, 0, stream>>>(w_v, wb, n8w);
        JO = {xf, wb, b_v, VTb, nullptr, 1, 1.0f};
        gemm128<<<g1, blk, 0, stream>>>(JO, JO, JO);
        flash_fuzzy<<<fg, blk, 0, stream>>>(Qb, Kb, VTb, lutp, AO);
        cast_bf16<<<cw, blk, 0, stream>>>(w_o, wb, n8w);
        JO = {AO, wb, b_o, nullptr, (float*)d_out, 2, 1.0f};
        gemm128<<<g1, blk, 0, stream>>>(JO, JO, JO);
    }
}

// Round 14
// 253.469 us; speedup vs baseline: 1.1727x; 1.0269x over previous
//
#include <hip/hip_runtime.h>
#include <hip/hip_bf16.h>

// SimpleFuzzyAttention: B=2, S=2048, D=1024, H=16, DK=64
// fz(s) is univariate -> packed bf16 (v0, delta) LUT of g(s)=exp(fz(s)-bound);
// bound = 16/temp (analytic max of fz); constant cancels in softmax.
// R17: XCD-locality block remap in gemm128 (ONE change vs R16). R16 counters:
// QKV gemm 77.5us, FETCH 101.6MB (~3.3x input), MfmaUtil 12.6, VALU 7.7,
// 1.9TB/s -> latency-bound on HBM-miss staging. Cause: XCD = blockIdx.x
// (global linear id mod 8 = x since gridDim.x=8), so each XCD streamed ALL
// of A through its 4MB L2. Remap: n-tile = y&7, m-tile = x*4 + (y>>3) ->
// XCD k owns m-panels [4k,4k+4) x all n: A 1MB/job L2-resident (8x reuse),
// W 2MB resident. Flash/prep/O-dispatch structure unchanged (R11-best).

#define S_LEN 2048
#define DMODEL 1024
#define NHEAD 16
#define DKH 64
#define NLUT 2048
#define LUT_MIN (-10.0f)
#define LUT_MAX (10.0f)

typedef __attribute__((ext_vector_type(8))) short bfx8;   // 8 bf16 (4 VGPRs)
typedef __attribute__((ext_vector_type(4))) float fx4;    // MFMA C/D 16x16
typedef __attribute__((ext_vector_type(16))) float fx16;  // MFMA C/D 32x32
typedef __attribute__((ext_vector_type(4))) unsigned ux4;

__device__ __forceinline__ short f2bf(float x) {
    unsigned u = __builtin_bit_cast(unsigned, x);
    u = (u + 0x7fffu + ((u >> 16) & 1u)) >> 16;   // RNE
    return (short)u;
}

__device__ __forceinline__ unsigned cvt_pk_bf16(float lo, float hi) {
    unsigned r;
    asm("v_cvt_pk_bf16_f32 %0, %1, %2" : "=v"(r) : "v"(lo), "v"(hi));
    return r;
}

// v_permlane32_swap_b32: after, a = {a_lo, b_lo}, b = {a_hi, b_hi}.
__device__ __forceinline__ void plane_swap(unsigned& a, unsigned& b) {
    asm volatile("v_permlane32_swap_b32 %0, %1" : "+v"(a), "+v"(b));
}

__device__ __forceinline__ void stage8_f32(const float* __restrict__ src, short* dst) {
    float4 a = *(const float4*)(src);
    float4 b = *(const float4*)(src + 4);
    bfx8 r;
    r[0] = f2bf(a.x); r[1] = f2bf(a.y); r[2] = f2bf(a.z); r[3] = f2bf(a.w);
    r[4] = f2bf(b.x); r[5] = f2bf(b.y); r[6] = f2bf(b.z); r[7] = f2bf(b.w);
    *(bfx8*)dst = r;
}

// global -> LDS direct 16B copy (LDS base wave-uniform; lane*16 implied)
__device__ __forceinline__ void gload_lds16(const void* g, void* l) {
    __builtin_amdgcn_global_load_lds(
        (const __attribute__((address_space(1))) unsigned int*)g,
        (__attribute__((address_space(3))) unsigned int*)l, 16, 0, 0);
}

// ---------------------------------------------------------------------------
// Parallel LUT slice: 8 blocks x 256 points. lutp[j] = bf16(g[j]) |
// bf16(g[j+1]-g[j])<<16, g = exp(fz - 16/temp). No division, no reduction.
// ---------------------------------------------------------------------------
__device__ void lut_slice(const float* __restrict__ centers, const float* __restrict__ widths,
                          const float* __restrict__ temp, unsigned* __restrict__ lutp,
                          int slice) {
    __shared__ float cs[48], iw[48];
    __shared__ float gsh[257];
    int tid = threadIdx.x;
    if (tid < 48) {
        cs[tid] = centers[tid];
        float w = widths[tid];
        iw[tid] = -0.5f / (w * w);
    }
    __syncthreads();
    float invT = 1.0f / temp[0];
    const float step = (LUT_MAX - LUT_MIN) / (float)(NLUT - 1);
    float bound = 16.0f * invT;
    int base = slice * 256;
    #pragma unroll 1
    for (int idx = tid; idx < 257; idx += 256) {   // tid 0 also does the halo
        int i = base + idx; if (i > NLUT - 1) i = NLUT - 1;
        float s = LUT_MIN + step * (float)i;
        float a = 0.0f;
        #pragma unroll
        for (int j = 0; j < 48; j++) {
            float d = s - cs[j];
            a += expf(d * d * iw[j]);
        }
        float fz = a * (1.0f / 3.0f) * invT;
        gsh[idx] = expf(fz - bound);
    }
    __syncthreads();
    float g0 = gsh[tid];
    unsigned lo = (unsigned short)f2bf(g0);
    unsigned hi = (unsigned short)f2bf(gsh[tid + 1] - g0);
    lutp[base + tid] = lo | (hi << 16);
}

__global__ void build_lut_pk(const float* centers, const float* widths,
                             const float* temp, unsigned* lutp) {
    lut_slice(centers, widths, temp, lutp, blockIdx.x);
}

// ---------------------------------------------------------------------------
// fp32 -> bf16 cast (fallback path), 8 elems/thread
// ---------------------------------------------------------------------------
__global__ void cast_bf16(const float* __restrict__ src, short* __restrict__ dst, int n8) {
    int i = blockIdx.x * 256 + threadIdx.x;
    if (i < n8) stage8_f32(src + (size_t)i * 8, dst + (size_t)i * 8);
}

// ---------------------------------------------------------------------------
// Fused prep: grid 1032. Blocks [0,1024) grid-stride the 8192 copy units
// ([0,6144)=inputs, [6144,8192)=weights); blocks [1024,1032) build the LUT.
// ---------------------------------------------------------------------------
__global__ void prep_all(const float* q, const float* kin, const float* v,
        const float* wq, const float* wk, const float* wv, const float* wo,
        short* xq, short* xk, short* xv,
        short* bwq, short* bwk, short* bwv, short* bwo,
        const float* centers, const float* widths, const float* temp,
        unsigned* lutp) {
    int bid = blockIdx.x;
    if (bid >= 1024) {
        lut_slice(centers, widths, temp, lutp, bid - 1024);
        return;
    }
    for (int vb = bid; vb < 8192; vb += 1024) {
        const float* src; short* dst; int blk;
        if (vb < 6144) {
            int y = vb >> 11; blk = vb & 2047;
            src = (y == 0) ? q : (y == 1) ? kin : v;
            dst = (y == 0) ? xq : (y == 1) ? xk : xv;
        } else {
            int y = (vb - 6144) >> 9; blk = (vb - 6144) & 511;
            src = (y == 0) ? wq : (y == 1) ? wk : (y == 2) ? wv : wo;
            dst = (y == 0) ? bwq : (y == 1) ? bwk : (y == 2) ? bwv : bwo;
        }
        size_t i = (size_t)blk * 256 + threadIdx.x;   // always in range (exact)
        stage8_f32(src + i * 8, (short*)dst + i * 8);
    }
}

// ---------------------------------------------------------------------------
// bf16 BT-GEMM, 128x128 tile, BK=32, double-buffered, launch_bounds(256,3).
// XCD-locality remap: XCD = blockIdx.x (global lin id % 8); n-tile = y&7,
// m-tile = x*4 + (y>>3) -> each XCD owns 4 m-panels x all 8 n-tiles, with
// n sweeping fastest in arrival order (A-panel 8x L2 reuse, W resident).
// C[m,n] = (sum_k A[m,k]*W[n,k] + bias[n]) * scale.
// mode 0: bf16 [B,H,S,DK]; 1: bf16 [B,H,DK,S]; 2: fp32 [M,N]
// ---------------------------------------------------------------------------
struct GemmJob {
    const short* A; const short* W; const float* bias;
    short* obf; float* of32; int mode; float scale;
};

__global__ __launch_bounds__(256, 3) void gemm128(GemmJob j0, GemmJob j1, GemmJob j2) {
    __shared__ __align__(16) short As[2][128 * 32];   // 2 x 8 KB, swizzled
    __shared__ __align__(16) short Bs[2][128 * 32];   // 2 x 8 KB
    GemmJob jb = (blockIdx.z == 0) ? j0 : (blockIdx.z == 1) ? j1 : j2;
    int tid = threadIdx.x, wave = tid >> 6, lane = tid & 63, quad = lane >> 4, l15 = lane & 15;
    int xr = blockIdx.y & 7;                       // n-tile
    int yr = blockIdx.x * 4 + (blockIdx.y >> 3);   // m-tile (XCD-chunked)
    int m0 = yr * 128, n0 = xr * 128;
    int wm = (wave >> 1) * 64, wn = (wave & 1) * 64;

    fx4 acc[4][4];
    #pragma unroll
    for (int i = 0; i < 4; i++)
        #pragma unroll
        for (int j = 0; j < 4; j++)
            #pragma unroll
            for (int r = 0; r < 4; r++) acc[i][j][r] = 0.0f;

    int fc = (quad ^ ((l15 >> 1) & 3)) * 8;        // swizzled frag chunk (shorts)

    // staging lane geometry (constant): 512 slots of 16B per buffer
    int srow[2], sgc[2];
    #pragma unroll
    for (int r = 0; r < 2; r++) {
        int slot = r * 256 + wave * 64 + lane;     // -> 128 rows x 4 chunks
        srow[r] = slot >> 2;
        sgc[r] = (slot & 3) ^ ((srow[r] >> 1) & 3);
    }

    auto stage = [&](int k0, int buf) {
        #pragma unroll
        for (int r = 0; r < 2; r++) {
            gload_lds16(jb.A + (size_t)(m0 + srow[r]) * DMODEL + k0 + sgc[r] * 8,
                        &As[buf][(r * 256 + wave * 64) * 8]);
            gload_lds16(jb.W + (size_t)(n0 + srow[r]) * DMODEL + k0 + sgc[r] * 8,
                        &Bs[buf][(r * 256 + wave * 64) * 8]);
        }
    };

    stage(0, 0);
    __syncthreads();                 // vmcnt(0) drain of prologue stage
    int buf = 0;
    for (int k0 = 0; k0 < DMODEL; k0 += 32) {
        if (k0 + 32 < DMODEL) stage(k0 + 32, buf ^ 1);   // prefetch next tile
        bfx8 af[4], bfr[4];
        #pragma unroll
        for (int i = 0; i < 4; i++) af[i] = *(const bfx8*)(&As[buf][(wm + i * 16 + l15) * 32 + fc]);
        #pragma unroll
        for (int j = 0; j < 4; j++) bfr[j] = *(const bfx8*)(&Bs[buf][(wn + j * 16 + l15) * 32 + fc]);
        #pragma unroll
        for (int i = 0; i < 4; i++)
            #pragma unroll
            for (int j = 0; j < 4; j++)
                acc[i][j] = __builtin_amdgcn_mfma_f32_16x16x32_bf16(af[i], bfr[j], acc[i][j], 0, 0, 0);
        __syncthreads();             // drains prefetch (had full compute to fly)
        buf ^= 1;
    }

    // epilogue: C/D layout col=lane&15 (n), row=quad*4+reg (m)
    #pragma unroll
    for (int j = 0; j < 4; j++) {
        int n = n0 + wn + j * 16 + l15;
        float bv = jb.bias[n];
        #pragma unroll
        for (int i = 0; i < 4; i++) {
            #pragma unroll
            for (int r = 0; r < 4; r++) {
                int m = m0 + wm + i * 16 + quad * 4 + r;
                float v = (acc[i][j][r] + bv) * jb.scale;
                if (jb.mode == 0) {
                    int b = m >> 11, s = m & 2047, h = n >> 6, dk = n & 63;
                    jb.obf[(((size_t)(b * NHEAD + h)) * S_LEN + s) * DKH + dk] = f2bf(v);
                } else if (jb.mode == 1) {
                    int b = m >> 11, s = m & 2047, h = n >> 6, dk = n & 63;
                    jb.obf[(((size_t)(b * NHEAD + h)) * DKH + dk) * S_LEN + s] = f2bf(v);
                } else {
                    jb.of32[(size_t)m * DMODEL + n] = v;
                }
            }
        }
    }
}

// ---------------------------------------------------------------------------
// Fuzzy flash attention, R16 structure (measured ~75.5 us): 32x32x16 MFMA,
// in-register P; K/V staged in LDS with phi(r)=(r^(r>>3))&7 swizzle; single
// (v0,delta) LUT; den via ones-MFMA; launch_bounds(256,4) — do NOT raise
// (R10: forcing 6 waves/EU spilled accumulators, 2.5x regression).
// ---------------------------------------------------------------------------
__global__ __launch_bounds__(256, 4) void flash_fuzzy(const short* __restrict__ Qb,
        const short* __restrict__ Kb, const short* __restrict__ VTb,
        const unsigned* __restrict__ lutg, short* __restrict__ AO) {
    __shared__ __align__(16) short Ks[64 * 64];     // 8 KB [kv][dk], phi-swizzled
    __shared__ __align__(16) short Vs[64 * 64];     // 8 KB [dk][kv], phi-swizzled
    __shared__ unsigned lut[NLUT];                  // 8 KB (v0, delta) bf16 pairs
    __shared__ float dbuf[128];                     // den exchange

    int tid = threadIdx.x, wave = tid >> 6, lane = tid & 63;
    int l31 = lane & 31, hi = lane >> 5;
    int wq = wave >> 1, st = wave & 1;
    int q0 = blockIdx.x * 64, bh = blockIdx.y;
    const short* Qp = Qb + (size_t)bh * S_LEN * DKH;
    const short* Kp = Kb + (size_t)bh * S_LEN * DKH;
    const short* Vp = VTb + (size_t)bh * DKH * S_LEN;

    #pragma unroll
    for (int i = tid; i < NLUT / 4; i += 256)
        ((uint4*)lut)[i] = ((const uint4*)lutg)[i];

    // Q as B-operand: lane supplies B[k=hi*8+j][q=l31] = Q[q0+wq*32+l31][k]
    bfx8 aq[4];
    #pragma unroll
    for (int ks = 0; ks < 4; ks++)
        aq[ks] = *(const bfx8*)(Qp + (size_t)(q0 + wq * 32 + l31) * DKH + ks * 16 + hi * 8);

    bfx8 ones;
    #pragma unroll
    for (int i = 0; i < 8; i++) ones[i] = (short)0x3F80;  // bf16 1.0

    fx16 oacc[2];
    fx16 dacc;
    #pragma unroll
    for (int r = 0; r < 16; r++) dacc[r] = 0.0f;
    #pragma unroll
    for (int dt = 0; dt < 2; dt++)
        #pragma unroll
        for (int r = 0; r < 16; r++) oacc[dt][r] = 0.0f;

    const float invh = (float)(NLUT - 1) / (LUT_MAX - LUT_MIN);
    const float xoff = -LUT_MIN * invh;

    // staging geometry: 512 slots of 16B per buffer, 2 per thread;
    // chunk swizzled by phi(row) = (row ^ (row>>3)) & 7
    int srow[2], sgc[2];
    #pragma unroll
    for (int r = 0; r < 2; r++) {
        int slot = (wave * 2 + r) * 64 + lane;
        srow[r] = slot >> 3;
        sgc[r] = (slot & 7) ^ ((srow[r] ^ (srow[r] >> 3)) & 7);
    }

    int krow = st * 32 + l31;
    int kphi = (krow ^ (krow >> 3)) & 7;

    for (int t0 = 0; t0 < S_LEN; t0 += 64) {
        __syncthreads();                 // all waves done reading tile t0-64
        #pragma unroll
        for (int r = 0; r < 2; r++) {
            gload_lds16(Kp + (size_t)(t0 + srow[r]) * DKH + sgc[r] * 8,
                        &Ks[((wave * 2 + r) * 64) * 8]);
            gload_lds16(Vp + (size_t)srow[r] * S_LEN + t0 + sgc[r] * 8,
                        &Vs[((wave * 2 + r) * 64) * 8]);
        }
        __syncthreads();                 // staging complete

        // S^T[kv32 (this wave's half)][q32] = K . Q^T over dk=64 (4 k-steps)
        fx16 sac;
        #pragma unroll
        for (int r = 0; r < 16; r++) sac[r] = 0.0f;
        #pragma unroll
        for (int ks = 0; ks < 4; ks++) {
            bfx8 kf = *(const bfx8*)(&Ks[krow * 64 + (((ks * 2 + hi) ^ kphi) * 8)]);
            sac = __builtin_amdgcn_mfma_f32_32x32x16_bf16(kf, aq[ks], sac, 0, 0, 0);
        }

        // p = g(s): one b32 (v0, delta) gather + fma lerp; pack pairs to bf16
        unsigned w[8];
        #pragma unroll
        for (int t = 0; t < 8; t++) {
            float pv[2];
            #pragma unroll
            for (int u = 0; u < 2; u++) {
                float s = sac[t * 2 + u];
                float x = fmaf(s, invh, xoff);
                x = __builtin_amdgcn_fmed3f(x, 0.0f, (float)(NLUT - 1));
                int j = (int)x;                          // v_cvt_i32_f32
                float f = __builtin_amdgcn_fractf(x);    // v_fract_f32 (x>=0)
                unsigned pr = lut[j];
                float v0 = __builtin_bit_cast(float, pr << 16);
                float dl = __builtin_bit_cast(float, pr & 0xffff0000u);
                pv[u] = fmaf(f, dl, v0);
            }
            w[t] = cvt_pk_bf16(pv[0], pv[1]);
        }

        // redistribute across lane halves -> PV B-fragments
        plane_swap(w[0], w[2]); plane_swap(w[1], w[3]);
        plane_swap(w[4], w[6]); plane_swap(w[5], w[7]);
        ux4 b0v = {w[0], w[1], w[2], w[3]};
        ux4 b1v = {w[4], w[5], w[6], w[7]};
        bfx8 pb0 = __builtin_bit_cast(bfx8, b0v);
        bfx8 pb1 = __builtin_bit_cast(bfx8, b1v);

        // O^T[dk][q] += VT . P^T   (2 dk-tiles x 2 k-steps)
        #pragma unroll
        for (int dt = 0; dt < 2; dt++) {
            int row = dt * 32 + l31;
            int vphi = (row ^ (row >> 3)) & 7;
            bfx8 v0f = *(const bfx8*)(&Vs[row * 64 + (((st * 4 + 0 + hi) ^ vphi) * 8)]);
            bfx8 v1f = *(const bfx8*)(&Vs[row * 64 + (((st * 4 + 2 + hi) ^ vphi) * 8)]);
            oacc[dt] = __builtin_amdgcn_mfma_f32_32x32x16_bf16(v0f, pb0, oacc[dt], 0, 0, 0);
            oacc[dt] = __builtin_amdgcn_mfma_f32_32x32x16_bf16(v1f, pb1, oacc[dt], 0, 0, 0);
        }
        // den[q] += sum_kv P[kv][q] on the matrix pipe (rows all equal)
        dacc = __builtin_amdgcn_mfma_f32_32x32x16_bf16(ones, pb0, dacc, 0, 0, 0);
        dacc = __builtin_amdgcn_mfma_f32_32x32x16_bf16(ones, pb1, dacc, 0, 0, 0);
    }

    float den = dacc[0];   // den[q=l31] for this wave's kv-half (rows equal)

    // combine kv halves: st=1 waves stash to LDS (Ks/Vs dead), st=0 finalize
    __syncthreads();
    float* obuf = (wq == 0) ? (float*)Ks : (float*)Vs;   // 8 KB each
    if (st == 1) {
        #pragma unroll
        for (int dt = 0; dt < 2; dt++)
            #pragma unroll
            for (int r = 0; r < 16; r++)
                obuf[(dt * 16 + r) * 64 + lane] = oacc[dt][r];
        dbuf[wq * 64 + lane] = den;
    }
    __syncthreads();
    if (st == 0) {
        float dtot = den + dbuf[wq * 64 + lane];
        int b = bh >> 4, h = bh & 15;
        #pragma unroll
        for (int dt = 0; dt < 2; dt++) {
            #pragma unroll
            for (int r = 0; r < 16; r++) {
                float o = oacc[dt][r] + obuf[(dt * 16 + r) * 64 + lane];
                int dk = dt * 32 + (r & 3) + 8 * (r >> 2) + 4 * hi;
                int q = q0 + wq * 32 + l31;
                AO[((size_t)(b * S_LEN + q)) * DMODEL + h * DKH + dk] = f2bf(o / dtot);
            }
        }
    }
}

// ---------------------------------------------------------------------------
extern "C" void kernel_launch(void* const* d_in, const int* in_sizes, int n_in,
                              void* d_out, int out_size, void* d_ws, size_t ws_size,
                              hipStream_t stream) {
    const float* query   = (const float*)d_in[0];
    const float* key_in  = (const float*)d_in[1];
    const float* value   = (const float*)d_in[2];
    const float* w_q     = (const float*)d_in[3];
    const float* b_q     = (const float*)d_in[4];
    const float* w_k     = (const float*)d_in[5];
    const float* b_k     = (const float*)d_in[6];
    const float* w_v     = (const float*)d_in[7];
    const float* b_v     = (const float*)d_in[8];
    const float* w_o     = (const float*)d_in[9];
    const float* b_o     = (const float*)d_in[10];
    const float* centers = (const float*)d_in[11];
    const float* widths  = (const float*)d_in[12];
    const float* temp    = (const float*)d_in[13];

    char* p = (char*)d_ws;
    auto alloc = [&](size_t bytes) -> void* {
        void* r = (void*)p;
        p += (bytes + 255) & ~(size_t)255;
        return r;
    };
    const size_t nBHSD = (size_t)2 * NHEAD * S_LEN * DKH;    // 4.19M elems
    const size_t nW    = (size_t)DMODEL * DMODEL;            // 1.05M elems
    unsigned* lutp = (unsigned*)alloc(NLUT * 4);
    short* Qb  = (short*)alloc(nBHSD * 2);
    short* Kb  = (short*)alloc(nBHSD * 2);
    short* VTb = (short*)alloc(nBHSD * 2);

    char* save = p;
    short* xq  = (short*)alloc(nBHSD * 2);
    short* xk  = (short*)alloc(nBHSD * 2);
    short* xv  = (short*)alloc(nBHSD * 2);
    short* bwq = (short*)alloc(nW * 2);
    short* bwk = (short*)alloc(nW * 2);
    short* bwv = (short*)alloc(nW * 2);
    short* bwo = (short*)alloc(nW * 2);
    bool fused = ((size_t)(p - (char*)d_ws) <= ws_size);

    dim3 blk(256);
    dim3 gq(8, 32, 3), g1(8, 32, 1), fg(32, 32);
    GemmJob JO;

    if (fused) {
        short* AO = xq;   // alias: xq dead after QKV gemm
        prep_all<<<dim3(1032), blk, 0, stream>>>(query, key_in, value, w_q, w_k, w_v, w_o,
                xq, xk, xv, bwq, bwk, bwv, bwo, centers, widths, temp, lutp);
        GemmJob JQ = {xq, bwq, b_q, Qb,  nullptr, 0, 0.125f};   // 1/sqrt(64) folded
        GemmJob JK = {xk, bwk, b_k, Kb,  nullptr, 0, 1.0f};
        GemmJob JV = {xv, bwv, b_v, VTb, nullptr, 1, 1.0f};
        gemm128<<<gq, blk, 0, stream>>>(JQ, JK, JV);
        flash_fuzzy<<<fg, blk, 0, stream>>>(Qb, Kb, VTb, lutp, AO);
        JO = {AO, bwo, b_o, nullptr, (float*)d_out, 2, 1.0f};
        gemm128<<<g1, blk, 0, stream>>>(JO, JO, JO);
    } else {
        // serial fallback: reuse one x-buffer + one w-buffer (~36 MB total)
        p = save;
        short* xf = (short*)alloc(nBHSD * 2);
        short* wb = (short*)alloc(nW * 2);
        short* AO = xf;
        const int n8x = (int)(nBHSD / 8), n8w = (int)(nW / 8);
        dim3 cg((n8x + 255) / 256), cw((n8w + 255) / 256);
        build_lut_pk<<<dim3(8), blk, 0, stream>>>(centers, widths, temp, lutp);
        cast_bf16<<<cg, blk, 0, stream>>>(query, xf, n8x);
        cast_bf16<<<cw, blk, 0, stream>>>(w_q, wb, n8w);
        JO = {xf, wb, b_q, Qb, nullptr, 0, 0.125f};
        gemm128<<<g1, blk, 0, stream>>>(JO, JO, JO);
        cast_bf16<<<cg, blk, 0, stream>>>(key_in, xf, n8x);
        cast_bf16<<<cw, blk, 0, stream>>>(w_k, wb, n8w);
        JO = {xf, wb, b_k, Kb, nullptr, 0, 1.0f};
        gemm128<<<g1, blk, 0, stream>>>(JO, JO, JO);
        cast_bf16<<<cg, blk, 0, stream>>>(value, xf, n8x);
        cast_bf16<<<cw, blk, 0, stream>>>(w_v, wb, n8w);
        JO = {xf, wb, b_v, VTb, nullptr, 1, 1.0f};
        gemm128<<<g1, blk, 0, stream>>>(JO, JO, JO);
        flash_fuzzy<<<fg, blk, 0, stream>>>(Qb, Kb, VTb, lutp, AO);
        cast_bf16<<<cw, blk, 0, stream>>>(w_o, wb, n8w);
        JO = {AO, wb, b_o, nullptr, (float*)d_out, 2, 1.0f};
        gemm128<<<g1, blk, 0, stream>>>(JO, JO, JO);
    }
}